// Round 8
// baseline (384.380 us; speedup 1.0000x reference)
//
#include <hip/hip_runtime.h>

#define NN 100000
#define NE 1600000
#define DF 128
#define TS 136    // LDS row stride in u16: 272 B -> 2-way (free) bank aliasing on frag reads
#define NCB 391   // coarse buckets: dst>>8, 256 nodes each
#define NWA 256   // pass-A workgroups (wg-private regions scale with this)
#define SZA 6250  // edges per pass-A stripe (NE/NWA)
#define NH (NCB * NWA)  // 100096
#define CAPB 6144 // pass-B LDS seg capacity (mean 4092 edges/cb, +32 sigma)

typedef unsigned int uint32;
typedef unsigned short u16;
typedef _Float16 f16;
typedef f16 f16x8 __attribute__((ext_vector_type(8)));
typedef f16 f16x2 __attribute__((ext_vector_type(2)));
typedef float f32x4 __attribute__((ext_vector_type(4)));

// ---- fp16 helpers ----
__device__ __forceinline__ uint32 pk2(float a, float b) {
    union { f16x2 h; uint32 u; } v;
    v.h.x = (f16)a; v.h.y = (f16)b;
    return v.u;
}
__device__ __forceinline__ u16 f2h(float a) {
    union { f16 h; u16 u; } v; v.h = (f16)a; return v.u;
}

// ================= CSR build: two-pass counting sort =================
// R5 lesson: gather kernels stay zero-LDS / max-occupancy. R7 lesson:
// launch-boundary overhead is ~1us/launch -- launch merging is done.
// R8: gather split per-panel (diagnostic: lets >27us kernels surface in
// top-5); GEMMs restructured to full-128 B-tile (3 barriers, not 7).

// blocks 0..NWA-1:        coarse hist (also atomicAdd -> CBT)
// blocks NWA..NWA+319:    weight prep fp32 [k][n] -> fp16 [n][k]
// blocks NWA+320..:       x fp32 -> fp16
__global__ __launch_bounds__(256) void histA_prep(
    const int* __restrict__ dst, int* __restrict__ H, int* __restrict__ CBT,
    const float* __restrict__ Ws0, const float* __restrict__ Wn0,
    const float* __restrict__ Ws1, const float* __restrict__ Wn1,
    const float* __restrict__ Ws2, const float* __restrict__ Wn2,
    u16* __restrict__ WB,
    const float* __restrict__ x, uint2* __restrict__ xh) {
    __shared__ int lh[NCB];
    int b = blockIdx.x, t = threadIdx.x;
    if (b < NWA) {
        int w = b;
        for (int i = t; i < NCB; i += 256) lh[i] = 0;
        __syncthreads();
        int e0 = w * SZA, e1 = min(e0 + SZA, NE);
        for (int e = e0 + t; e < e1; e += 256) atomicAdd(&lh[dst[e] >> 8], 1);
        __syncthreads();
        for (int i = t; i < NCB; i += 256) {
            int v = lh[i];
            H[i * NWA + w] = v;
            if (v) atomicAdd(&CBT[i], v);  // CBT zeroed by memset node each replay
        }
    } else if (b < NWA + 320) {
        int u = (b - NWA) * 256 + t;  // 0 .. 81919
        if (u < 65536) {
            int m = u >> 14;           // 0..3
            int local = u & 16383;
            int k = local >> 7, n = local & 127;
            const float* W = (m == 0) ? Ws0 : (m == 1) ? Wn0 : (m == 2) ? Ws1 : Wn1;
            WB[m * 16384 + n * 128 + k] = f2h(W[k * 128 + n]);
        } else {
            int local = u - 65536;     // 0 .. 16383
            int half = local >> 13;    // 0 = Ws2, 1 = Wn2
            int idx = local & 8191;
            int k = idx >> 6, n = idx & 63;
            const float* W = half ? Wn2 : Ws2;
            WB[4 * 16384 + (n + half * 64) * 128 + k] = f2h(W[k * 64 + n]);
        }
    } else {
        int u = (b - NWA - 320) * 256 + t;
        if (u < NN * DF / 4) {
            float4 v = ((const float4*)x)[u];
            uint2 o;
            o.x = pk2(v.x, v.y);
            o.y = pk2(v.z, v.w);
            xh[u] = o;
        }
    }
}

// levels 2+3 FUSED: each of 391 wgs redundantly scans the 391
// coarse-bucket totals in LDS, then does its per-cb scan of 256 counts.
__global__ __launch_bounds__(512) void scanCBW(const int* __restrict__ CBT,
                                               const int* __restrict__ H,
                                               int* __restrict__ O,
                                               int* __restrict__ rowptr) {
    __shared__ int sm[512];
    __shared__ int sh[256];
    int cb = blockIdx.x, t = threadIdx.x;
    int v = (t < NCB) ? CBT[t] : 0;
    sm[t] = v;
    __syncthreads();
    for (int off = 1; off < 512; off <<= 1) {
        int x = (t >= off) ? sm[t - off] : 0;
        __syncthreads();
        sm[t] += x;
        __syncthreads();
    }
    if (cb == 0 && t == NCB - 1) {
        O[NH] = sm[t];       // = NE
        rowptr[NN] = sm[t];  // = NE
    }
    int cbo = sm[cb] - CBT[cb];
    int hv = (t < 256) ? H[cb * NWA + t] : 0;
    if (t < 256) sh[t] = hv;
    __syncthreads();
    for (int off = 1; off < 256; off <<= 1) {
        int x = (t >= off && t < 256) ? sh[t - off] : 0;
        __syncthreads();
        if (t < 256) sh[t] += x;
        __syncthreads();
    }
    if (t < 256) O[cb * NWA + t] = cbo + sh[t] - hv;
}

__global__ __launch_bounds__(1024) void passA(const int* __restrict__ src,
                                              const int* __restrict__ dst,
                                              const int* __restrict__ O,
                                              uint32* __restrict__ ebuf) {
    __shared__ int cur[NCB];
    int w = blockIdx.x, t = threadIdx.x;
    for (int i = t; i < NCB; i += 1024) cur[i] = O[i * NWA + w];
    __syncthreads();
    int e0 = w * SZA, e1 = min(e0 + SZA, NE);
    for (int e = e0 + t; e < e1; e += 1024) {
        int d = dst[e];
        int cb = d >> 8;
        int p = atomicAdd(&cur[cb], 1);  // LDS atomic; region private to this wg
        ebuf[p] = ((uint32)src[e] << 8) | (uint32)(d & 255);
    }
}

__global__ __launch_bounds__(256) void passB(const uint32* __restrict__ ebuf,
                                             const int* __restrict__ O,
                                             int* __restrict__ rowptr,
                                             int* __restrict__ col) {
    __shared__ int hist[256], start[256], cur[256];
    __shared__ int seg[CAPB];
    int cb = blockIdx.x, t = threadIdx.x;
    int base = O[cb * NWA], end = O[(cb + 1) * NWA];
    int m = end - base;
    hist[t] = 0;
    __syncthreads();
    for (int i = t; i < m; i += 256) atomicAdd(&hist[ebuf[base + i] & 255], 1);
    __syncthreads();
    int v = hist[t];
    cur[t] = v;
    __syncthreads();
    for (int off = 1; off < 256; off <<= 1) {
        int x = (t >= off) ? cur[t - off] : 0;
        __syncthreads();
        cur[t] += x;
        __syncthreads();
    }
    start[t] = cur[t] - v;
    __syncthreads();
    int node = cb * 256 + t;
    if (node < NN) rowptr[node] = base + start[t];
    cur[t] = start[t];
    __syncthreads();
    if (m <= CAPB) {  // fast path: sort into LDS, stream out coalesced
        for (int i = t; i < m; i += 256) {
            uint32 u = ebuf[base + i];
            int p = atomicAdd(&cur[u & 255], 1);
            seg[p] = (int)(u >> 8);
        }
        __syncthreads();
        for (int i = t; i < m; i += 256) col[base + i] = seg[i];
    } else {  // correctness fallback
        for (int i = t; i < m; i += 256) {
            uint32 u = ebuf[base + i];
            int p = atomicAdd(&cur[u & 255], 1);
            col[base + p] = (int)(u >> 8);
        }
    }
}

// ================= gather mean, fp16 in/out, one 64-col panel ============
// hb/mean are PRE-OFFSET by the panel (0 or +64 u16 = 128B). 8 lanes/node,
// dwordx4 per lane per neighbor, unroll 8, zero LDS. Per-panel launch
// (R8 diagnostic: two ~27us dispatches instead of one 53us).
__global__ __launch_bounds__(256) void gather_f16(const u16* __restrict__ hb,
                                                  const int* __restrict__ rowptr,
                                                  const int* __restrict__ col,
                                                  u16* __restrict__ mean) {
    int node = blockIdx.x * 32 + (threadIdx.x >> 3);
    int g = threadIdx.x & 7;                   // 16B chunk within 128B panel
    const u16* hp = hb + g * 8;
    int s = rowptr[node], e = rowptr[node + 1];
    float acc[8];
#pragma unroll
    for (int i = 0; i < 8; ++i) acc[i] = 0.f;
    int j = s;
    for (; j + 7 < e; j += 8) {
        int n0 = col[j],     n1 = col[j + 1], n2 = col[j + 2], n3 = col[j + 3];
        int n4 = col[j + 4], n5 = col[j + 5], n6 = col[j + 6], n7 = col[j + 7];
        f16x8 v0 = *(const f16x8*)(hp + (size_t)n0 * DF);
        f16x8 v1 = *(const f16x8*)(hp + (size_t)n1 * DF);
        f16x8 v2 = *(const f16x8*)(hp + (size_t)n2 * DF);
        f16x8 v3 = *(const f16x8*)(hp + (size_t)n3 * DF);
        f16x8 v4 = *(const f16x8*)(hp + (size_t)n4 * DF);
        f16x8 v5 = *(const f16x8*)(hp + (size_t)n5 * DF);
        f16x8 v6 = *(const f16x8*)(hp + (size_t)n6 * DF);
        f16x8 v7 = *(const f16x8*)(hp + (size_t)n7 * DF);
        f16x8 sA = (v0 + v1) + (v2 + v3);
        f16x8 sB = (v4 + v5) + (v6 + v7);
#pragma unroll
        for (int i = 0; i < 8; ++i) acc[i] += (float)sA[i] + (float)sB[i];
    }
    for (; j + 3 < e; j += 4) {
        int n0 = col[j], n1 = col[j + 1], n2 = col[j + 2], n3 = col[j + 3];
        f16x8 v0 = *(const f16x8*)(hp + (size_t)n0 * DF);
        f16x8 v1 = *(const f16x8*)(hp + (size_t)n1 * DF);
        f16x8 v2 = *(const f16x8*)(hp + (size_t)n2 * DF);
        f16x8 v3 = *(const f16x8*)(hp + (size_t)n3 * DF);
        f16x8 sv = (v0 + v1) + (v2 + v3);
#pragma unroll
        for (int i = 0; i < 8; ++i) acc[i] += (float)sv[i];
    }
    for (; j < e; ++j) {
        f16x8 v = *(const f16x8*)(hp + (size_t)col[j] * DF);
#pragma unroll
        for (int i = 0; i < 8; ++i) acc[i] += (float)v[i];
    }
    float invd = 1.f / fmaxf((float)(e - s), 1.f);
    union { f16x8 h; uint4 u; } o;
#pragma unroll
    for (int i = 0; i < 8; ++i) o.h[i] = (f16)(acc[i] * invd);
    *(uint4*)(mean + (size_t)node * DF + g * 8) = o.u;
}

// ================= gather mean-add, fp16 in, width 64, into fp32 out =========
__global__ __launch_bounds__(256) void gather_add_f16(const u16* __restrict__ gb,
                                                      const int* __restrict__ rowptr,
                                                      const int* __restrict__ col,
                                                      float* __restrict__ out) {
    int node = blockIdx.x * 32 + (threadIdx.x >> 3);
    int g = threadIdx.x & 7;  // 16B chunk within the 128B row
    int s = rowptr[node], e = rowptr[node + 1];
    float acc[8];
#pragma unroll
    for (int i = 0; i < 8; ++i) acc[i] = 0.f;
    int j = s;
    for (; j + 7 < e; j += 8) {
        int n0 = col[j],     n1 = col[j + 1], n2 = col[j + 2], n3 = col[j + 3];
        int n4 = col[j + 4], n5 = col[j + 5], n6 = col[j + 6], n7 = col[j + 7];
        f16x8 v0 = *(const f16x8*)(gb + (size_t)n0 * 64 + g * 8);
        f16x8 v1 = *(const f16x8*)(gb + (size_t)n1 * 64 + g * 8);
        f16x8 v2 = *(const f16x8*)(gb + (size_t)n2 * 64 + g * 8);
        f16x8 v3 = *(const f16x8*)(gb + (size_t)n3 * 64 + g * 8);
        f16x8 v4 = *(const f16x8*)(gb + (size_t)n4 * 64 + g * 8);
        f16x8 v5 = *(const f16x8*)(gb + (size_t)n5 * 64 + g * 8);
        f16x8 v6 = *(const f16x8*)(gb + (size_t)n6 * 64 + g * 8);
        f16x8 v7 = *(const f16x8*)(gb + (size_t)n7 * 64 + g * 8);
        f16x8 sA = (v0 + v1) + (v2 + v3);
        f16x8 sB = (v4 + v5) + (v6 + v7);
#pragma unroll
        for (int i = 0; i < 8; ++i) acc[i] += (float)sA[i] + (float)sB[i];
    }
    for (; j + 3 < e; j += 4) {
        int n0 = col[j], n1 = col[j + 1], n2 = col[j + 2], n3 = col[j + 3];
        f16x8 v0 = *(const f16x8*)(gb + (size_t)n0 * 64 + g * 8);
        f16x8 v1 = *(const f16x8*)(gb + (size_t)n1 * 64 + g * 8);
        f16x8 v2 = *(const f16x8*)(gb + (size_t)n2 * 64 + g * 8);
        f16x8 v3 = *(const f16x8*)(gb + (size_t)n3 * 64 + g * 8);
        f16x8 sv = (v0 + v1) + (v2 + v3);
#pragma unroll
        for (int i = 0; i < 8; ++i) acc[i] += (float)sv[i];
    }
    for (; j < e; ++j) {
        f16x8 v = *(const f16x8*)(gb + (size_t)col[j] * 64 + g * 8);
#pragma unroll
        for (int i = 0; i < 8; ++i) acc[i] += (float)v[i];
    }
    float invd = 1.f / fmaxf((float)(e - s), 1.f);
    float4* op = (float4*)(out + (size_t)node * 64 + g * 8);
    float4 a = op[0], b = op[1];
    a.x += acc[0] * invd; a.y += acc[1] * invd;
    a.z += acc[2] * invd; a.w += acc[3] * invd;
    b.x += acc[4] * invd; b.y += acc[5] * invd;
    b.z += acc[6] * invd; b.w += acc[7] * invd;
    op[0] = a; op[1] = b;
}

// ================= MFMA GEMM building blocks (fp16) ======
// R8: full 128-row weight tile per GEMM; 3 barriers/gemm_sage (was 7);
// A-fragments loaded once per phase, reused across all 8 n-tiles.
// LDS 69.6 KB -> 2 blocks/CU (GEMM is staging/barrier-bound, not occ-bound).
__device__ __forceinline__ void stage_a(u16* sm, const u16* g, int row0, int tid) {
#pragma unroll
    for (int i = 0; i < 8; ++i) {
        int idx = i * 256 + tid;
        int r = idx >> 4, c = (idx & 15) * 8;
        uint4 v = make_uint4(0, 0, 0, 0);
        int gr = row0 + r;
        if (gr < NN) v = *(const uint4*)(g + (size_t)gr * DF + c);
        *(uint4*)(sm + r * TS + c) = v;
    }
}

__device__ __forceinline__ void stage_w128(u16* sm, const u16* wt, int tid) {
#pragma unroll
    for (int i = 0; i < 8; ++i) {
        int idx = i * 256 + tid;
        int r = idx >> 4, c = (idx & 15) * 8;
        *(uint4*)(sm + r * TS + c) = *(const uint4*)(wt + (size_t)r * 128 + c);
    }
}

__device__ __forceinline__ f16x8 frag(const u16* sm, int row, int lane, int kc) {
    return *(const f16x8*)(sm + (row + (lane & 15)) * TS + kc * 32 + (lane >> 4) * 8);
}

__device__ __forceinline__ void mfma8(const u16* As, const u16* Bs, int wrow, int lane,
                                      f32x4 acc[2][8]) {
    f16x8 a[2][4];
#pragma unroll
    for (int rt = 0; rt < 2; ++rt)
#pragma unroll
        for (int kc = 0; kc < 4; ++kc) a[rt][kc] = frag(As, wrow + rt * 16, lane, kc);
#pragma unroll
    for (int n = 0; n < 8; ++n) {
#pragma unroll
        for (int kc = 0; kc < 4; ++kc) {
            f16x8 b = frag(Bs, n * 16, lane, kc);
            acc[0][n] = __builtin_amdgcn_mfma_f32_16x16x32_f16(a[0][kc], b, acc[0][n], 0, 0, 0);
            acc[1][n] = __builtin_amdgcn_mfma_f32_16x16x32_f16(a[1][kc], b, acc[1][n], 0, 0, 0);
        }
    }
}

// ---- fused SAGE layer (DO=128): OutH = fp16(relu(H@Ws + M@Wn + b)), in-place safe
__global__ __launch_bounds__(256) void gemm_sage_f16(
    const u16* H, const u16* M,
    const u16* __restrict__ Ws, const u16* __restrict__ Wn,
    const float* __restrict__ bias, u16* OutH) {
    __shared__ u16 As[128 * TS];
    __shared__ u16 Bs[128 * TS];
    const int tid = threadIdx.x;
    const int lane = tid & 63;
    const int wrow = (tid >> 6) * 32;
    const int row0 = blockIdx.x * 128;

    f32x4 acc[2][8];
#pragma unroll
    for (int rt = 0; rt < 2; ++rt)
#pragma unroll
        for (int n = 0; n < 8; ++n) acc[rt][n] = {0.f, 0.f, 0.f, 0.f};

    stage_a(As, H, row0, tid);
    stage_w128(Bs, Ws, tid);
    __syncthreads();
    mfma8(As, Bs, wrow, lane, acc);
    __syncthreads();
    stage_a(As, M, row0, tid);
    stage_w128(Bs, Wn, tid);
    __syncthreads();
    mfma8(As, Bs, wrow, lane, acc);

    const int cit = lane & 15;
    const int rq = (lane >> 4) * 4;
#pragma unroll
    for (int rt = 0; rt < 2; ++rt)
#pragma unroll
        for (int n = 0; n < 8; ++n) {
            float bv = bias[n * 16 + cit];
            f32x4 v = acc[rt][n];
#pragma unroll
            for (int r = 0; r < 4; ++r) {
                int gr = row0 + wrow + rt * 16 + rq + r;
                if (gr < NN) {
                    float o = fmaxf(v[r] + bv, 0.f);
                    OutH[(size_t)gr * DF + n * 16 + cit] = f2h(o);
                }
            }
        }
}

// ---- layer 2 (128 packed cols): n 0-63 -> out = H@Ws2 + b2 (fp32);
//      n 64-127 -> g2 = H@Wn2 (fp16). W2 rows 0-63 = Ws2^T, 64-127 = Wn2^T.
__global__ __launch_bounds__(256) void gemm_l2_f16(
    const u16* __restrict__ H, const u16* __restrict__ W2,
    const float* __restrict__ b2, float* __restrict__ out, u16* __restrict__ g2) {
    __shared__ u16 As[128 * TS];
    __shared__ u16 Bs[128 * TS];
    const int tid = threadIdx.x;
    const int lane = tid & 63;
    const int wrow = (tid >> 6) * 32;
    const int row0 = blockIdx.x * 128;

    f32x4 acc[2][8];
#pragma unroll
    for (int rt = 0; rt < 2; ++rt)
#pragma unroll
        for (int n = 0; n < 8; ++n) acc[rt][n] = {0.f, 0.f, 0.f, 0.f};

    stage_a(As, H, row0, tid);
    stage_w128(Bs, W2, tid);
    __syncthreads();
    mfma8(As, Bs, wrow, lane, acc);

    const int cit = lane & 15;
    const int rq = (lane >> 4) * 4;
#pragma unroll
    for (int rt = 0; rt < 2; ++rt)
#pragma unroll
        for (int n = 0; n < 8; ++n) {
            f32x4 v = acc[rt][n];
            float bv = (n < 4) ? b2[n * 16 + cit] : 0.f;
#pragma unroll
            for (int r = 0; r < 4; ++r) {
                int gr = row0 + wrow + rt * 16 + rq + r;
                if (gr < NN) {
                    if (n < 4) out[(size_t)gr * 64 + n * 16 + cit] = v[r] + bv;
                    else g2[(size_t)gr * 64 + (n - 4) * 16 + cit] = f2h(v[r]);
                }
            }
        }
}

extern "C" void kernel_launch(void* const* d_in, const int* in_sizes, int n_in,
                              void* d_out, int out_size, void* d_ws, size_t ws_size,
                              hipStream_t stream) {
    const float* x   = (const float*)d_in[0];
    const int*   src = (const int*)d_in[1];
    const int*   dst = (const int*)d_in[2];
    const float* Ws0 = (const float*)d_in[3];
    const float* Wn0 = (const float*)d_in[4];
    const float* b0  = (const float*)d_in[5];
    const float* Ws1 = (const float*)d_in[6];
    const float* Wn1 = (const float*)d_in[7];
    const float* b1  = (const float*)d_in[8];
    const float* Ws2 = (const float*)d_in[9];
    const float* Wn2 = (const float*)d_in[10];
    const float* b2  = (const float*)d_in[11];
    float* out = (float*)d_out;

    // workspace (~66 MB):
    int* H       = (int*)d_ws;                 // NH (100096)
    int* O       = H + NH;                     // NH+1 (alloc 100352)
    int* CBT     = O + 100352;                 // NCB (alloc 512)
    int* CBO     = CBT + 512;                  // NCB (alloc 512; unused)
    int* rowptr  = CBO + 512;                  // NN+1 (alloc 100352)
    int* col     = rowptr + 100352;            // NE
    uint32* ebuf = (uint32*)(col + NE);        // NE
    u16* WB      = (u16*)(ebuf + NE);          // 5 * 16384
    u16* W0s = WB, *W0n = WB + 16384, *W1s = WB + 2 * 16384, *W1n = WB + 3 * 16384;
    u16* W2  = WB + 4 * 16384;
    u16* P1 = WB + 5 * 16384;                  // fp16 x -> h1 -> h2 (in-place)
    u16* P3 = P1 + (size_t)NN * DF;            // fp16 mean0 -> mean1 -> g2

    const int gB = (NN + 127) / 128;           // 782
    const int gG = NN / 32;                    // 3125 (per panel)

    // ---- front end: CBT zero + (hist | weight-prep | x-cvt) in one dispatch ----
    hipMemsetAsync(CBT, 0, NCB * sizeof(int), stream);
    histA_prep<<<NWA + 320 + NN * DF / 4 / 256, 256, 0, stream>>>(
        dst, H, CBT, Ws0, Wn0, Ws1, Wn1, Ws2, Wn2, WB, x, (uint2*)P1);

    // ---- CSR: scan + two-pass counting sort ----
    scanCBW<<<NCB, 512, 0, stream>>>(CBT, H, O, rowptr);
    passA<<<NWA, 1024, 0, stream>>>(src, dst, O, ebuf);
    passB<<<NCB, 256, 0, stream>>>(ebuf, O, rowptr, col);

    // ---- layer 0 (gather split per panel) ----
    gather_f16<<<gG, 256, 0, stream>>>(P1,      rowptr, col, P3);
    gather_f16<<<gG, 256, 0, stream>>>(P1 + 64, rowptr, col, P3 + 64);
    gemm_sage_f16<<<gB, 256, 0, stream>>>(P1, P3, W0s, W0n, b0, P1);

    // ---- layer 1 ----
    gather_f16<<<gG, 256, 0, stream>>>(P1,      rowptr, col, P3);
    gather_f16<<<gG, 256, 0, stream>>>(P1 + 64, rowptr, col, P3 + 64);
    gemm_sage_f16<<<gB, 256, 0, stream>>>(P1, P3, W1s, W1n, b1, P1);

    // ---- layer 2 (transform-then-aggregate) ----
    gemm_l2_f16<<<gB, 256, 0, stream>>>(P1, W2, b2, out, P3);
    gather_add_f16<<<NN / 32, 256, 0, stream>>>(P3, rowptr, col, out);
}

// Round 9
// 374.459 us; speedup vs baseline: 1.0265x; 1.0265x over previous
//
#include <hip/hip_runtime.h>

#define NN 100000
#define NE 1600000
#define DF 128
#define TS 136    // LDS row stride in u16: 272 B -> 2-way (free) bank aliasing on frag reads
#define NCB 391   // coarse buckets: dst>>8, 256 nodes each
#define NWA 256   // pass-A workgroups (wg-private regions scale with this)
#define SZA 6250  // edges per pass-A stripe (NE/NWA)
#define NH (NCB * NWA)  // 100096
#define CAPB 6144 // pass-B LDS seg capacity (mean 4092 edges/cb, +32 sigma)

typedef unsigned int uint32;
typedef unsigned short u16;
typedef _Float16 f16;
typedef f16 f16x8 __attribute__((ext_vector_type(8)));
typedef f16 f16x2 __attribute__((ext_vector_type(2)));
typedef float f32x4 __attribute__((ext_vector_type(4)));

// ---- fp16 helpers ----
__device__ __forceinline__ uint32 pk2(float a, float b) {
    union { f16x2 h; uint32 u; } v;
    v.h.x = (f16)a; v.h.y = (f16)b;
    return v.u;
}
__device__ __forceinline__ u16 f2h(float a) {
    union { f16 h; u16 u; } v; v.h = (f16)a; return v.u;
}

// ================= CSR build: two-pass counting sort =================
// R5: gathers stay zero-LDS/max-occupancy (no gather+GEMM fusion).
// R7: launch merging exhausted (~1us/boundary). R8: top-5 visibility is
// dead -- harness's 256MiB workspace poison fill (~41us/iter, in-stream)
// floods it; all our kernels are <41us. Budget from arithmetic only.

// blocks 0..NWA-1:        coarse hist (also atomicAdd -> CBT)
// blocks NWA..NWA+319:    weight prep fp32 [k][n] -> fp16 [n][k]
// blocks NWA+320..:       x fp32 -> fp16
__global__ __launch_bounds__(256) void histA_prep(
    const int* __restrict__ dst, int* __restrict__ H, int* __restrict__ CBT,
    const float* __restrict__ Ws0, const float* __restrict__ Wn0,
    const float* __restrict__ Ws1, const float* __restrict__ Wn1,
    const float* __restrict__ Ws2, const float* __restrict__ Wn2,
    u16* __restrict__ WB,
    const float* __restrict__ x, uint2* __restrict__ xh) {
    __shared__ int lh[NCB];
    int b = blockIdx.x, t = threadIdx.x;
    if (b < NWA) {
        int w = b;
        for (int i = t; i < NCB; i += 256) lh[i] = 0;
        __syncthreads();
        int e0 = w * SZA, e1 = min(e0 + SZA, NE);
        for (int e = e0 + t; e < e1; e += 256) atomicAdd(&lh[dst[e] >> 8], 1);
        __syncthreads();
        for (int i = t; i < NCB; i += 256) {
            int v = lh[i];
            H[i * NWA + w] = v;
            if (v) atomicAdd(&CBT[i], v);  // CBT zeroed by memset node each replay
        }
    } else if (b < NWA + 320) {
        int u = (b - NWA) * 256 + t;  // 0 .. 81919
        if (u < 65536) {
            int m = u >> 14;           // 0..3
            int local = u & 16383;
            int k = local >> 7, n = local & 127;
            const float* W = (m == 0) ? Ws0 : (m == 1) ? Wn0 : (m == 2) ? Ws1 : Wn1;
            WB[m * 16384 + n * 128 + k] = f2h(W[k * 128 + n]);
        } else {
            int local = u - 65536;     // 0 .. 16383
            int half = local >> 13;    // 0 = Ws2, 1 = Wn2
            int idx = local & 8191;
            int k = idx >> 6, n = idx & 63;
            const float* W = half ? Wn2 : Ws2;
            WB[4 * 16384 + (n + half * 64) * 128 + k] = f2h(W[k * 64 + n]);
        }
    } else {
        int u = (b - NWA - 320) * 256 + t;
        if (u < NN * DF / 4) {
            float4 v = ((const float4*)x)[u];
            uint2 o;
            o.x = pk2(v.x, v.y);
            o.y = pk2(v.z, v.w);
            xh[u] = o;
        }
    }
}

// levels 2+3 FUSED: each of 391 wgs redundantly scans the 391
// coarse-bucket totals in LDS, then does its per-cb scan of 256 counts.
__global__ __launch_bounds__(512) void scanCBW(const int* __restrict__ CBT,
                                               const int* __restrict__ H,
                                               int* __restrict__ O,
                                               int* __restrict__ rowptr) {
    __shared__ int sm[512];
    __shared__ int sh[256];
    int cb = blockIdx.x, t = threadIdx.x;
    int v = (t < NCB) ? CBT[t] : 0;
    sm[t] = v;
    __syncthreads();
    for (int off = 1; off < 512; off <<= 1) {
        int x = (t >= off) ? sm[t - off] : 0;
        __syncthreads();
        sm[t] += x;
        __syncthreads();
    }
    if (cb == 0 && t == NCB - 1) {
        O[NH] = sm[t];       // = NE
        rowptr[NN] = sm[t];  // = NE
    }
    int cbo = sm[cb] - CBT[cb];
    int hv = (t < 256) ? H[cb * NWA + t] : 0;
    if (t < 256) sh[t] = hv;
    __syncthreads();
    for (int off = 1; off < 256; off <<= 1) {
        int x = (t >= off && t < 256) ? sh[t - off] : 0;
        __syncthreads();
        if (t < 256) sh[t] += x;
        __syncthreads();
    }
    if (t < 256) O[cb * NWA + t] = cbo + sh[t] - hv;
}

__global__ __launch_bounds__(1024) void passA(const int* __restrict__ src,
                                              const int* __restrict__ dst,
                                              const int* __restrict__ O,
                                              uint32* __restrict__ ebuf) {
    __shared__ int cur[NCB];
    int w = blockIdx.x, t = threadIdx.x;
    for (int i = t; i < NCB; i += 1024) cur[i] = O[i * NWA + w];
    __syncthreads();
    int e0 = w * SZA, e1 = min(e0 + SZA, NE);
    for (int e = e0 + t; e < e1; e += 1024) {
        int d = dst[e];
        int cb = d >> 8;
        int p = atomicAdd(&cur[cb], 1);  // LDS atomic; region private to this wg
        ebuf[p] = ((uint32)src[e] << 8) | (uint32)(d & 255);
    }
}

__global__ __launch_bounds__(256) void passB(const uint32* __restrict__ ebuf,
                                             const int* __restrict__ O,
                                             int* __restrict__ rowptr,
                                             int* __restrict__ col) {
    __shared__ int hist[256], start[256], cur[256];
    __shared__ int seg[CAPB];
    int cb = blockIdx.x, t = threadIdx.x;
    int base = O[cb * NWA], end = O[(cb + 1) * NWA];
    int m = end - base;
    hist[t] = 0;
    __syncthreads();
    for (int i = t; i < m; i += 256) atomicAdd(&hist[ebuf[base + i] & 255], 1);
    __syncthreads();
    int v = hist[t];
    cur[t] = v;
    __syncthreads();
    for (int off = 1; off < 256; off <<= 1) {
        int x = (t >= off) ? cur[t - off] : 0;
        __syncthreads();
        cur[t] += x;
        __syncthreads();
    }
    start[t] = cur[t] - v;
    __syncthreads();
    int node = cb * 256 + t;
    if (node < NN) rowptr[node] = base + start[t];
    cur[t] = start[t];
    __syncthreads();
    if (m <= CAPB) {  // fast path: sort into LDS, stream out coalesced
        for (int i = t; i < m; i += 256) {
            uint32 u = ebuf[base + i];
            int p = atomicAdd(&cur[u & 255], 1);
            seg[p] = (int)(u >> 8);
        }
        __syncthreads();
        for (int i = t; i < m; i += 256) col[base + i] = seg[i];
    } else {  // correctness fallback
        for (int i = t; i < m; i += 256) {
            uint32 u = ebuf[base + i];
            int p = atomicAdd(&cur[u & 255], 1);
            col[base + p] = (int)(u >> 8);
        }
    }
}

// ================= gather mean, fp16 in/out, width 128 ==================
// Single launch, panel = bid&1 (128-B L2-line panels, 20 MB fetch saving
// vs full-row). 8 lanes/node, dwordx4/lane/neighbor, unroll 8, zero LDS.
// At the measured ~3.5 TB/s random-line fill ceiling (R4: 2x MLP = -3%).
__global__ __launch_bounds__(256) void gather_f16(const u16* __restrict__ hb,
                                                  const int* __restrict__ rowptr,
                                                  const int* __restrict__ col,
                                                  u16* __restrict__ mean) {
    int bid = blockIdx.x;
    int panel = bid & 1;                       // 0: cols 0-63, 1: cols 64-127
    int node = (bid >> 1) * 32 + (threadIdx.x >> 3);
    int g = threadIdx.x & 7;                   // 16B chunk within 128B panel
    const u16* hp = hb + panel * 64 + g * 8;
    int s = rowptr[node], e = rowptr[node + 1];
    float acc[8];
#pragma unroll
    for (int i = 0; i < 8; ++i) acc[i] = 0.f;
    int j = s;
    for (; j + 7 < e; j += 8) {
        int n0 = col[j],     n1 = col[j + 1], n2 = col[j + 2], n3 = col[j + 3];
        int n4 = col[j + 4], n5 = col[j + 5], n6 = col[j + 6], n7 = col[j + 7];
        f16x8 v0 = *(const f16x8*)(hp + (size_t)n0 * DF);
        f16x8 v1 = *(const f16x8*)(hp + (size_t)n1 * DF);
        f16x8 v2 = *(const f16x8*)(hp + (size_t)n2 * DF);
        f16x8 v3 = *(const f16x8*)(hp + (size_t)n3 * DF);
        f16x8 v4 = *(const f16x8*)(hp + (size_t)n4 * DF);
        f16x8 v5 = *(const f16x8*)(hp + (size_t)n5 * DF);
        f16x8 v6 = *(const f16x8*)(hp + (size_t)n6 * DF);
        f16x8 v7 = *(const f16x8*)(hp + (size_t)n7 * DF);
        f16x8 sA = (v0 + v1) + (v2 + v3);
        f16x8 sB = (v4 + v5) + (v6 + v7);
#pragma unroll
        for (int i = 0; i < 8; ++i) acc[i] += (float)sA[i] + (float)sB[i];
    }
    for (; j + 3 < e; j += 4) {
        int n0 = col[j], n1 = col[j + 1], n2 = col[j + 2], n3 = col[j + 3];
        f16x8 v0 = *(const f16x8*)(hp + (size_t)n0 * DF);
        f16x8 v1 = *(const f16x8*)(hp + (size_t)n1 * DF);
        f16x8 v2 = *(const f16x8*)(hp + (size_t)n2 * DF);
        f16x8 v3 = *(const f16x8*)(hp + (size_t)n3 * DF);
        f16x8 sv = (v0 + v1) + (v2 + v3);
#pragma unroll
        for (int i = 0; i < 8; ++i) acc[i] += (float)sv[i];
    }
    for (; j < e; ++j) {
        f16x8 v = *(const f16x8*)(hp + (size_t)col[j] * DF);
#pragma unroll
        for (int i = 0; i < 8; ++i) acc[i] += (float)v[i];
    }
    float invd = 1.f / fmaxf((float)(e - s), 1.f);
    union { f16x8 h; uint4 u; } o;
#pragma unroll
    for (int i = 0; i < 8; ++i) o.h[i] = (f16)(acc[i] * invd);
    *(uint4*)(mean + (size_t)node * DF + panel * 64 + g * 8) = o.u;
}

// ========== gather mean-add, fp16 in, width 64: out = self + mean(g2) =====
// R9: self term comes in as fp16 (written by gemm_l2), out written ONCE
// as fp32 -- removes the 25.6MB fp32 out read-modify-write round trip.
__global__ __launch_bounds__(256) void gather_add_f16(const u16* __restrict__ gb,
                                                      const u16* __restrict__ selfb,
                                                      const int* __restrict__ rowptr,
                                                      const int* __restrict__ col,
                                                      float* __restrict__ out) {
    int node = blockIdx.x * 32 + (threadIdx.x >> 3);
    int g = threadIdx.x & 7;  // 16B chunk within the 128B row
    int s = rowptr[node], e = rowptr[node + 1];
    float acc[8];
#pragma unroll
    for (int i = 0; i < 8; ++i) acc[i] = 0.f;
    int j = s;
    for (; j + 7 < e; j += 8) {
        int n0 = col[j],     n1 = col[j + 1], n2 = col[j + 2], n3 = col[j + 3];
        int n4 = col[j + 4], n5 = col[j + 5], n6 = col[j + 6], n7 = col[j + 7];
        f16x8 v0 = *(const f16x8*)(gb + (size_t)n0 * 64 + g * 8);
        f16x8 v1 = *(const f16x8*)(gb + (size_t)n1 * 64 + g * 8);
        f16x8 v2 = *(const f16x8*)(gb + (size_t)n2 * 64 + g * 8);
        f16x8 v3 = *(const f16x8*)(gb + (size_t)n3 * 64 + g * 8);
        f16x8 v4 = *(const f16x8*)(gb + (size_t)n4 * 64 + g * 8);
        f16x8 v5 = *(const f16x8*)(gb + (size_t)n5 * 64 + g * 8);
        f16x8 v6 = *(const f16x8*)(gb + (size_t)n6 * 64 + g * 8);
        f16x8 v7 = *(const f16x8*)(gb + (size_t)n7 * 64 + g * 8);
        f16x8 sA = (v0 + v1) + (v2 + v3);
        f16x8 sB = (v4 + v5) + (v6 + v7);
#pragma unroll
        for (int i = 0; i < 8; ++i) acc[i] += (float)sA[i] + (float)sB[i];
    }
    for (; j + 3 < e; j += 4) {
        int n0 = col[j], n1 = col[j + 1], n2 = col[j + 2], n3 = col[j + 3];
        f16x8 v0 = *(const f16x8*)(gb + (size_t)n0 * 64 + g * 8);
        f16x8 v1 = *(const f16x8*)(gb + (size_t)n1 * 64 + g * 8);
        f16x8 v2 = *(const f16x8*)(gb + (size_t)n2 * 64 + g * 8);
        f16x8 v3 = *(const f16x8*)(gb + (size_t)n3 * 64 + g * 8);
        f16x8 sv = (v0 + v1) + (v2 + v3);
#pragma unroll
        for (int i = 0; i < 8; ++i) acc[i] += (float)sv[i];
    }
    for (; j < e; ++j) {
        f16x8 v = *(const f16x8*)(gb + (size_t)col[j] * 64 + g * 8);
#pragma unroll
        for (int i = 0; i < 8; ++i) acc[i] += (float)v[i];
    }
    float invd = 1.f / fmaxf((float)(e - s), 1.f);
    f16x8 sv = *(const f16x8*)(selfb + (size_t)node * 64 + g * 8);
    float4 a, b;
    a.x = (float)sv[0] + acc[0] * invd; a.y = (float)sv[1] + acc[1] * invd;
    a.z = (float)sv[2] + acc[2] * invd; a.w = (float)sv[3] + acc[3] * invd;
    b.x = (float)sv[4] + acc[4] * invd; b.y = (float)sv[5] + acc[5] * invd;
    b.z = (float)sv[6] + acc[6] * invd; b.w = (float)sv[7] + acc[7] * invd;
    float4* op = (float4*)(out + (size_t)node * 64 + g * 8);
    op[0] = a; op[1] = b;
}

// ================= MFMA GEMM building blocks (fp16) ======
// Full 128-row weight tile; 3 barriers/gemm_sage; A-frags reused across
// all 8 n-tiles. LDS 69.6 KB -> 2 blocks/CU (measured ~= R7's 3-block
// 7-barrier variant; kept for simplicity).
__device__ __forceinline__ void stage_a(u16* sm, const u16* g, int row0, int tid) {
#pragma unroll
    for (int i = 0; i < 8; ++i) {
        int idx = i * 256 + tid;
        int r = idx >> 4, c = (idx & 15) * 8;
        uint4 v = make_uint4(0, 0, 0, 0);
        int gr = row0 + r;
        if (gr < NN) v = *(const uint4*)(g + (size_t)gr * DF + c);
        *(uint4*)(sm + r * TS + c) = v;
    }
}

__device__ __forceinline__ void stage_w128(u16* sm, const u16* wt, int tid) {
#pragma unroll
    for (int i = 0; i < 8; ++i) {
        int idx = i * 256 + tid;
        int r = idx >> 4, c = (idx & 15) * 8;
        *(uint4*)(sm + r * TS + c) = *(const uint4*)(wt + (size_t)r * 128 + c);
    }
}

__device__ __forceinline__ f16x8 frag(const u16* sm, int row, int lane, int kc) {
    return *(const f16x8*)(sm + (row + (lane & 15)) * TS + kc * 32 + (lane >> 4) * 8);
}

__device__ __forceinline__ void mfma8(const u16* As, const u16* Bs, int wrow, int lane,
                                      f32x4 acc[2][8]) {
    f16x8 a[2][4];
#pragma unroll
    for (int rt = 0; rt < 2; ++rt)
#pragma unroll
        for (int kc = 0; kc < 4; ++kc) a[rt][kc] = frag(As, wrow + rt * 16, lane, kc);
#pragma unroll
    for (int n = 0; n < 8; ++n) {
#pragma unroll
        for (int kc = 0; kc < 4; ++kc) {
            f16x8 b = frag(Bs, n * 16, lane, kc);
            acc[0][n] = __builtin_amdgcn_mfma_f32_16x16x32_f16(a[0][kc], b, acc[0][n], 0, 0, 0);
            acc[1][n] = __builtin_amdgcn_mfma_f32_16x16x32_f16(a[1][kc], b, acc[1][n], 0, 0, 0);
        }
    }
}

// ---- fused SAGE layer (DO=128): OutH = fp16(relu(H@Ws + M@Wn + b)), in-place safe
__global__ __launch_bounds__(256) void gemm_sage_f16(
    const u16* H, const u16* M,
    const u16* __restrict__ Ws, const u16* __restrict__ Wn,
    const float* __restrict__ bias, u16* OutH) {
    __shared__ u16 As[128 * TS];
    __shared__ u16 Bs[128 * TS];
    const int tid = threadIdx.x;
    const int lane = tid & 63;
    const int wrow = (tid >> 6) * 32;
    const int row0 = blockIdx.x * 128;

    f32x4 acc[2][8];
#pragma unroll
    for (int rt = 0; rt < 2; ++rt)
#pragma unroll
        for (int n = 0; n < 8; ++n) acc[rt][n] = {0.f, 0.f, 0.f, 0.f};

    stage_a(As, H, row0, tid);
    stage_w128(Bs, Ws, tid);
    __syncthreads();
    mfma8(As, Bs, wrow, lane, acc);
    __syncthreads();
    stage_a(As, M, row0, tid);
    stage_w128(Bs, Wn, tid);
    __syncthreads();
    mfma8(As, Bs, wrow, lane, acc);

    const int cit = lane & 15;
    const int rq = (lane >> 4) * 4;
#pragma unroll
    for (int rt = 0; rt < 2; ++rt)
#pragma unroll
        for (int n = 0; n < 8; ++n) {
            float bv = bias[n * 16 + cit];
            f32x4 v = acc[rt][n];
#pragma unroll
            for (int r = 0; r < 4; ++r) {
                int gr = row0 + wrow + rt * 16 + rq + r;
                if (gr < NN) {
                    float o = fmaxf(v[r] + bv, 0.f);
                    OutH[(size_t)gr * DF + n * 16 + cit] = f2h(o);
                }
            }
        }
}

// ---- layer 2 (128 packed cols): n 0-63 -> selfb = fp16(H@Ws2 + b2);
//      n 64-127 -> g2 = fp16(H@Wn2). W2 rows 0-63 = Ws2^T, 64-127 = Wn2^T.
//      (R9: self term fp16 scratch; gather_add writes fp32 out once.)
__global__ __launch_bounds__(256) void gemm_l2_f16(
    const u16* __restrict__ H, const u16* __restrict__ W2,
    const float* __restrict__ b2, u16* __restrict__ selfb, u16* __restrict__ g2) {
    __shared__ u16 As[128 * TS];
    __shared__ u16 Bs[128 * TS];
    const int tid = threadIdx.x;
    const int lane = tid & 63;
    const int wrow = (tid >> 6) * 32;
    const int row0 = blockIdx.x * 128;

    f32x4 acc[2][8];
#pragma unroll
    for (int rt = 0; rt < 2; ++rt)
#pragma unroll
        for (int n = 0; n < 8; ++n) acc[rt][n] = {0.f, 0.f, 0.f, 0.f};

    stage_a(As, H, row0, tid);
    stage_w128(Bs, W2, tid);
    __syncthreads();
    mfma8(As, Bs, wrow, lane, acc);

    const int cit = lane & 15;
    const int rq = (lane >> 4) * 4;
#pragma unroll
    for (int rt = 0; rt < 2; ++rt)
#pragma unroll
        for (int n = 0; n < 8; ++n) {
            f32x4 v = acc[rt][n];
            float bv = (n < 4) ? b2[n * 16 + cit] : 0.f;
#pragma unroll
            for (int r = 0; r < 4; ++r) {
                int gr = row0 + wrow + rt * 16 + rq + r;
                if (gr < NN) {
                    if (n < 4) selfb[(size_t)gr * 64 + n * 16 + cit] = f2h(v[r] + bv);
                    else g2[(size_t)gr * 64 + (n - 4) * 16 + cit] = f2h(v[r]);
                }
            }
        }
}

extern "C" void kernel_launch(void* const* d_in, const int* in_sizes, int n_in,
                              void* d_out, int out_size, void* d_ws, size_t ws_size,
                              hipStream_t stream) {
    const float* x   = (const float*)d_in[0];
    const int*   src = (const int*)d_in[1];
    const int*   dst = (const int*)d_in[2];
    const float* Ws0 = (const float*)d_in[3];
    const float* Wn0 = (const float*)d_in[4];
    const float* b0  = (const float*)d_in[5];
    const float* Ws1 = (const float*)d_in[6];
    const float* Wn1 = (const float*)d_in[7];
    const float* b1  = (const float*)d_in[8];
    const float* Ws2 = (const float*)d_in[9];
    const float* Wn2 = (const float*)d_in[10];
    const float* b2  = (const float*)d_in[11];
    float* out = (float*)d_out;

    // workspace (~66 MB):
    int* H       = (int*)d_ws;                 // NH (100096)
    int* O       = H + NH;                     // NH+1 (alloc 100352)
    int* CBT     = O + 100352;                 // NCB (alloc 512)
    int* CBO     = CBT + 512;                  // NCB (alloc 512; unused)
    int* rowptr  = CBO + 512;                  // NN+1 (alloc 100352)
    int* col     = rowptr + 100352;            // NE
    uint32* ebuf = (uint32*)(col + NE);        // NE
    u16* WB      = (u16*)(ebuf + NE);          // 5 * 16384
    u16* W0s = WB, *W0n = WB + 16384, *W1s = WB + 2 * 16384, *W1n = WB + 3 * 16384;
    u16* W2  = WB + 4 * 16384;
    u16* P1 = WB + 5 * 16384;                  // fp16 x -> h1 -> h2 (in-place)
    u16* P3 = P1 + (size_t)NN * DF;            // fp16 mean0/mean1; then g2|self
    u16* G2   = P3;                            // layer-2 neighbor term (NN*64)
    u16* SELF = P3 + (size_t)NN * 64;          // layer-2 self term (NN*64)

    const int gB = (NN + 127) / 128;           // 782

    // ---- front end: CBT zero + (hist | weight-prep | x-cvt) in one dispatch ----
    hipMemsetAsync(CBT, 0, NCB * sizeof(int), stream);
    histA_prep<<<NWA + 320 + NN * DF / 4 / 256, 256, 0, stream>>>(
        dst, H, CBT, Ws0, Wn0, Ws1, Wn1, Ws2, Wn2, WB, x, (uint2*)P1);

    // ---- CSR: scan + two-pass counting sort ----
    scanCBW<<<NCB, 512, 0, stream>>>(CBT, H, O, rowptr);
    passA<<<NWA, 1024, 0, stream>>>(src, dst, O, ebuf);
    passB<<<NCB, 256, 0, stream>>>(ebuf, O, rowptr, col);

    // ---- layer 0 ----
    gather_f16<<<(NN / 32) * 2, 256, 0, stream>>>(P1, rowptr, col, P3);
    gemm_sage_f16<<<gB, 256, 0, stream>>>(P1, P3, W0s, W0n, b0, P1);

    // ---- layer 1 ----
    gather_f16<<<(NN / 32) * 2, 256, 0, stream>>>(P1, rowptr, col, P3);
    gemm_sage_f16<<<gB, 256, 0, stream>>>(P1, P3, W1s, W1n, b1, P1);

    // ---- layer 2 (transform-then-aggregate; self term fp16) ----
    gemm_l2_f16<<<gB, 256, 0, stream>>>(P1, W2, b2, SELF, G2);
    gather_add_f16<<<NN / 32, 256, 0, stream>>>(G2, SELF, rowptr, col, out);
}

// Round 10
// 371.355 us; speedup vs baseline: 1.0351x; 1.0084x over previous
//
#include <hip/hip_runtime.h>

#define NN 100000
#define NE 1600000
#define DF 128
#define NCB 391   // coarse buckets: dst>>8, 256 nodes each
#define NWA 256   // pass-A workgroups (wg-private regions scale with this)
#define SZA 6250  // edges per pass-A stripe (NE/NWA)
#define NH (NCB * NWA)  // 100096
#define CAPB 6144 // pass-B LDS seg capacity (mean 4092 edges/cb, +32 sigma)

typedef unsigned int uint32;
typedef unsigned short u16;
typedef _Float16 f16;
typedef f16 f16x8 __attribute__((ext_vector_type(8)));
typedef f16 f16x2 __attribute__((ext_vector_type(2)));
typedef float f32x4 __attribute__((ext_vector_type(4)));

// ---- fp16 helpers ----
__device__ __forceinline__ uint32 pk2(float a, float b) {
    union { f16x2 h; uint32 u; } v;
    v.h.x = (f16)a; v.h.y = (f16)b;
    return v.u;
}
__device__ __forceinline__ u16 f2h(float a) {
    union { f16 h; u16 u; } v; v.h = (f16)a; return v.u;
}

// ================= CSR build: two-pass counting sort =================
// R5: gathers stay zero-LDS/max-occupancy. R7: launch merging exhausted.
// R8: top-5 visibility dead (harness 256MiB poison fill ~41us in-stream).
// R10: GEMM staging -> async global_load_lds (width 16) into LINEAR LDS
// with chunk-XOR swizzle (pre-swizzled global src + swizzled ds_read,
// rule #21); 48KB LDS -> 3 blocks/CU.

// blocks 0..NWA-1:        coarse hist (also atomicAdd -> CBT)
// blocks NWA..NWA+319:    weight prep fp32 [k][n] -> fp16 [n][k]
// blocks NWA+320..:       x fp32 -> fp16
__global__ __launch_bounds__(256) void histA_prep(
    const int* __restrict__ dst, int* __restrict__ H, int* __restrict__ CBT,
    const float* __restrict__ Ws0, const float* __restrict__ Wn0,
    const float* __restrict__ Ws1, const float* __restrict__ Wn1,
    const float* __restrict__ Ws2, const float* __restrict__ Wn2,
    u16* __restrict__ WB,
    const float* __restrict__ x, uint2* __restrict__ xh) {
    __shared__ int lh[NCB];
    int b = blockIdx.x, t = threadIdx.x;
    if (b < NWA) {
        int w = b;
        for (int i = t; i < NCB; i += 256) lh[i] = 0;
        __syncthreads();
        int e0 = w * SZA, e1 = min(e0 + SZA, NE);
        for (int e = e0 + t; e < e1; e += 256) atomicAdd(&lh[dst[e] >> 8], 1);
        __syncthreads();
        for (int i = t; i < NCB; i += 256) {
            int v = lh[i];
            H[i * NWA + w] = v;
            if (v) atomicAdd(&CBT[i], v);  // CBT zeroed by memset node each replay
        }
    } else if (b < NWA + 320) {
        int u = (b - NWA) * 256 + t;  // 0 .. 81919
        if (u < 65536) {
            int m = u >> 14;           // 0..3
            int local = u & 16383;
            int k = local >> 7, n = local & 127;
            const float* W = (m == 0) ? Ws0 : (m == 1) ? Wn0 : (m == 2) ? Ws1 : Wn1;
            WB[m * 16384 + n * 128 + k] = f2h(W[k * 128 + n]);
        } else {
            int local = u - 65536;     // 0 .. 16383
            int half = local >> 13;    // 0 = Ws2, 1 = Wn2
            int idx = local & 8191;
            int k = idx >> 6, n = idx & 63;
            const float* W = half ? Wn2 : Ws2;
            WB[4 * 16384 + (n + half * 64) * 128 + k] = f2h(W[k * 64 + n]);
        }
    } else {
        int u = (b - NWA - 320) * 256 + t;
        if (u < NN * DF / 4) {
            float4 v = ((const float4*)x)[u];
            uint2 o;
            o.x = pk2(v.x, v.y);
            o.y = pk2(v.z, v.w);
            xh[u] = o;
        }
    }
}

// levels 2+3 FUSED: each of 391 wgs redundantly scans the 391
// coarse-bucket totals in LDS, then does its per-cb scan of 256 counts.
__global__ __launch_bounds__(512) void scanCBW(const int* __restrict__ CBT,
                                               const int* __restrict__ H,
                                               int* __restrict__ O,
                                               int* __restrict__ rowptr) {
    __shared__ int sm[512];
    __shared__ int sh[256];
    int cb = blockIdx.x, t = threadIdx.x;
    int v = (t < NCB) ? CBT[t] : 0;
    sm[t] = v;
    __syncthreads();
    for (int off = 1; off < 512; off <<= 1) {
        int x = (t >= off) ? sm[t - off] : 0;
        __syncthreads();
        sm[t] += x;
        __syncthreads();
    }
    if (cb == 0 && t == NCB - 1) {
        O[NH] = sm[t];       // = NE
        rowptr[NN] = sm[t];  // = NE
    }
    int cbo = sm[cb] - CBT[cb];
    int hv = (t < 256) ? H[cb * NWA + t] : 0;
    if (t < 256) sh[t] = hv;
    __syncthreads();
    for (int off = 1; off < 256; off <<= 1) {
        int x = (t >= off && t < 256) ? sh[t - off] : 0;
        __syncthreads();
        if (t < 256) sh[t] += x;
        __syncthreads();
    }
    if (t < 256) O[cb * NWA + t] = cbo + sh[t] - hv;
}

__global__ __launch_bounds__(1024) void passA(const int* __restrict__ src,
                                              const int* __restrict__ dst,
                                              const int* __restrict__ O,
                                              uint32* __restrict__ ebuf) {
    __shared__ int cur[NCB];
    int w = blockIdx.x, t = threadIdx.x;
    for (int i = t; i < NCB; i += 1024) cur[i] = O[i * NWA + w];
    __syncthreads();
    int e0 = w * SZA, e1 = min(e0 + SZA, NE);
    for (int e = e0 + t; e < e1; e += 1024) {
        int d = dst[e];
        int cb = d >> 8;
        int p = atomicAdd(&cur[cb], 1);  // LDS atomic; region private to this wg
        ebuf[p] = ((uint32)src[e] << 8) | (uint32)(d & 255);
    }
}

__global__ __launch_bounds__(256) void passB(const uint32* __restrict__ ebuf,
                                             const int* __restrict__ O,
                                             int* __restrict__ rowptr,
                                             int* __restrict__ col) {
    __shared__ int hist[256], start[256], cur[256];
    __shared__ int seg[CAPB];
    int cb = blockIdx.x, t = threadIdx.x;
    int base = O[cb * NWA], end = O[(cb + 1) * NWA];
    int m = end - base;
    hist[t] = 0;
    __syncthreads();
    for (int i = t; i < m; i += 256) atomicAdd(&hist[ebuf[base + i] & 255], 1);
    __syncthreads();
    int v = hist[t];
    cur[t] = v;
    __syncthreads();
    for (int off = 1; off < 256; off <<= 1) {
        int x = (t >= off) ? cur[t - off] : 0;
        __syncthreads();
        cur[t] += x;
        __syncthreads();
    }
    start[t] = cur[t] - v;
    __syncthreads();
    int node = cb * 256 + t;
    if (node < NN) rowptr[node] = base + start[t];
    cur[t] = start[t];
    __syncthreads();
    if (m <= CAPB) {  // fast path: sort into LDS, stream out coalesced
        for (int i = t; i < m; i += 256) {
            uint32 u = ebuf[base + i];
            int p = atomicAdd(&cur[u & 255], 1);
            seg[p] = (int)(u >> 8);
        }
        __syncthreads();
        for (int i = t; i < m; i += 256) col[base + i] = seg[i];
    } else {  // correctness fallback
        for (int i = t; i < m; i += 256) {
            uint32 u = ebuf[base + i];
            int p = atomicAdd(&cur[u & 255], 1);
            col[base + p] = (int)(u >> 8);
        }
    }
}

// ================= gather mean, fp16 in/out, width 128 ==================
// Single launch, panel = bid&1. 8 lanes/node, dwordx4/lane/neighbor,
// unroll 8, zero LDS. At the ~3 TB/s random-line fill-port ceiling.
__global__ __launch_bounds__(256) void gather_f16(const u16* __restrict__ hb,
                                                  const int* __restrict__ rowptr,
                                                  const int* __restrict__ col,
                                                  u16* __restrict__ mean) {
    int bid = blockIdx.x;
    int panel = bid & 1;                       // 0: cols 0-63, 1: cols 64-127
    int node = (bid >> 1) * 32 + (threadIdx.x >> 3);
    int g = threadIdx.x & 7;                   // 16B chunk within 128B panel
    const u16* hp = hb + panel * 64 + g * 8;
    int s = rowptr[node], e = rowptr[node + 1];
    float acc[8];
#pragma unroll
    for (int i = 0; i < 8; ++i) acc[i] = 0.f;
    int j = s;
    for (; j + 7 < e; j += 8) {
        int n0 = col[j],     n1 = col[j + 1], n2 = col[j + 2], n3 = col[j + 3];
        int n4 = col[j + 4], n5 = col[j + 5], n6 = col[j + 6], n7 = col[j + 7];
        f16x8 v0 = *(const f16x8*)(hp + (size_t)n0 * DF);
        f16x8 v1 = *(const f16x8*)(hp + (size_t)n1 * DF);
        f16x8 v2 = *(const f16x8*)(hp + (size_t)n2 * DF);
        f16x8 v3 = *(const f16x8*)(hp + (size_t)n3 * DF);
        f16x8 v4 = *(const f16x8*)(hp + (size_t)n4 * DF);
        f16x8 v5 = *(const f16x8*)(hp + (size_t)n5 * DF);
        f16x8 v6 = *(const f16x8*)(hp + (size_t)n6 * DF);
        f16x8 v7 = *(const f16x8*)(hp + (size_t)n7 * DF);
        f16x8 sA = (v0 + v1) + (v2 + v3);
        f16x8 sB = (v4 + v5) + (v6 + v7);
#pragma unroll
        for (int i = 0; i < 8; ++i) acc[i] += (float)sA[i] + (float)sB[i];
    }
    for (; j + 3 < e; j += 4) {
        int n0 = col[j], n1 = col[j + 1], n2 = col[j + 2], n3 = col[j + 3];
        f16x8 v0 = *(const f16x8*)(hp + (size_t)n0 * DF);
        f16x8 v1 = *(const f16x8*)(hp + (size_t)n1 * DF);
        f16x8 v2 = *(const f16x8*)(hp + (size_t)n2 * DF);
        f16x8 v3 = *(const f16x8*)(hp + (size_t)n3 * DF);
        f16x8 sv = (v0 + v1) + (v2 + v3);
#pragma unroll
        for (int i = 0; i < 8; ++i) acc[i] += (float)sv[i];
    }
    for (; j < e; ++j) {
        f16x8 v = *(const f16x8*)(hp + (size_t)col[j] * DF);
#pragma unroll
        for (int i = 0; i < 8; ++i) acc[i] += (float)v[i];
    }
    float invd = 1.f / fmaxf((float)(e - s), 1.f);
    union { f16x8 h; uint4 u; } o;
#pragma unroll
    for (int i = 0; i < 8; ++i) o.h[i] = (f16)(acc[i] * invd);
    *(uint4*)(mean + (size_t)node * DF + panel * 64 + g * 8) = o.u;
}

// ========== gather mean-add, fp16 in, width 64: out = self + mean(g2) =====
__global__ __launch_bounds__(256) void gather_add_f16(const u16* __restrict__ gb,
                                                      const u16* __restrict__ selfb,
                                                      const int* __restrict__ rowptr,
                                                      const int* __restrict__ col,
                                                      float* __restrict__ out) {
    int node = blockIdx.x * 32 + (threadIdx.x >> 3);
    int g = threadIdx.x & 7;  // 16B chunk within the 128B row
    int s = rowptr[node], e = rowptr[node + 1];
    float acc[8];
#pragma unroll
    for (int i = 0; i < 8; ++i) acc[i] = 0.f;
    int j = s;
    for (; j + 7 < e; j += 8) {
        int n0 = col[j],     n1 = col[j + 1], n2 = col[j + 2], n3 = col[j + 3];
        int n4 = col[j + 4], n5 = col[j + 5], n6 = col[j + 6], n7 = col[j + 7];
        f16x8 v0 = *(const f16x8*)(gb + (size_t)n0 * 64 + g * 8);
        f16x8 v1 = *(const f16x8*)(gb + (size_t)n1 * 64 + g * 8);
        f16x8 v2 = *(const f16x8*)(gb + (size_t)n2 * 64 + g * 8);
        f16x8 v3 = *(const f16x8*)(gb + (size_t)n3 * 64 + g * 8);
        f16x8 v4 = *(const f16x8*)(gb + (size_t)n4 * 64 + g * 8);
        f16x8 v5 = *(const f16x8*)(gb + (size_t)n5 * 64 + g * 8);
        f16x8 v6 = *(const f16x8*)(gb + (size_t)n6 * 64 + g * 8);
        f16x8 v7 = *(const f16x8*)(gb + (size_t)n7 * 64 + g * 8);
        f16x8 sA = (v0 + v1) + (v2 + v3);
        f16x8 sB = (v4 + v5) + (v6 + v7);
#pragma unroll
        for (int i = 0; i < 8; ++i) acc[i] += (float)sA[i] + (float)sB[i];
    }
    for (; j + 3 < e; j += 4) {
        int n0 = col[j], n1 = col[j + 1], n2 = col[j + 2], n3 = col[j + 3];
        f16x8 v0 = *(const f16x8*)(gb + (size_t)n0 * 64 + g * 8);
        f16x8 v1 = *(const f16x8*)(gb + (size_t)n1 * 64 + g * 8);
        f16x8 v2 = *(const f16x8*)(gb + (size_t)n2 * 64 + g * 8);
        f16x8 v3 = *(const f16x8*)(gb + (size_t)n3 * 64 + g * 8);
        f16x8 sv = (v0 + v1) + (v2 + v3);
#pragma unroll
        for (int i = 0; i < 8; ++i) acc[i] += (float)sv[i];
    }
    for (; j < e; ++j) {
        f16x8 v = *(const f16x8*)(gb + (size_t)col[j] * 64 + g * 8);
#pragma unroll
        for (int i = 0; i < 8; ++i) acc[i] += (float)v[i];
    }
    float invd = 1.f / fmaxf((float)(e - s), 1.f);
    f16x8 sv = *(const f16x8*)(selfb + (size_t)node * 64 + g * 8);
    float4 a, b;
    a.x = (float)sv[0] + acc[0] * invd; a.y = (float)sv[1] + acc[1] * invd;
    a.z = (float)sv[2] + acc[2] * invd; a.w = (float)sv[3] + acc[3] * invd;
    b.x = (float)sv[4] + acc[4] * invd; b.y = (float)sv[5] + acc[5] * invd;
    b.z = (float)sv[6] + acc[6] * invd; b.w = (float)sv[7] + acc[7] * invd;
    float4* op = (float4*)(out + (size_t)node * 64 + g * 8);
    op[0] = a; op[1] = b;
}

// ================= MFMA GEMM (fp16), async-staged =================
// Staging: global_load_lds width=16 into LINEAR LDS (wave-uniform base +
// lane*16B). Bank-conflict fix per rule #21: chunk-XOR swizzle applied on
// the GLOBAL source address AND on the ds_read frag address (both-sides).
// LDS[row][c] = G[row][c ^ (row&7)] (16B chunks); frag reads invert it.
// 16 lanes x 16 rows/frag-read land on 8 slots x 2 lanes = free 2-way.
// Staging reads stay full-line (XOR permutes within each 128B line).
__device__ __forceinline__ void gl_lds16(const u16* g, u16* l) {
    __builtin_amdgcn_global_load_lds(
        (const __attribute__((address_space(1))) void*)g,
        (__attribute__((address_space(3))) void*)l, 16, 0, 0);
}

// stage 128 rows of 256B from g into lds (linear, swizzled). 8 calls/wave.
__device__ __forceinline__ void stage128(u16* lds, const u16* g, int tid) {
    int lane = tid & 63, wid = tid >> 6;
#pragma unroll
    for (int i = 0; i < 8; ++i) {
        int r4 = (wid + i * 4) * 4;        // 4 rows per call, waves interleaved
        int row = r4 + (lane >> 4);
        int c = lane & 15;
        gl_lds16(g + (size_t)row * 128 + ((c ^ (row & 7)) * 8), lds + r4 * 128);
    }
}

// stage 64 rows (weight half). 4 calls/wave.
__device__ __forceinline__ void stage64(u16* lds, const u16* g, int tid) {
    int lane = tid & 63, wid = tid >> 6;
#pragma unroll
    for (int i = 0; i < 4; ++i) {
        int r4 = (wid + i * 4) * 4;
        int row = r4 + (lane >> 4);
        int c = lane & 15;
        gl_lds16(g + (size_t)row * 128 + ((c ^ (row & 7)) * 8), lds + r4 * 128);
    }
}

__device__ __forceinline__ f16x8 fragS(const u16* sm, int row, int lane, int kc) {
    int r = row + (lane & 15);
    int c = (kc * 4 + (lane >> 4)) ^ (r & 7);
    return *(const f16x8*)(sm + r * 128 + c * 8);
}

__device__ __forceinline__ void loadA(f16x8 a[2][4], const u16* As, int wrow, int lane) {
#pragma unroll
    for (int rt = 0; rt < 2; ++rt)
#pragma unroll
        for (int kc = 0; kc < 4; ++kc) a[rt][kc] = fragS(As, wrow + rt * 16, lane, kc);
}

// one 64-col weight half: n-tiles nb..nb+3
__device__ __forceinline__ void mfmaH(const f16x8 a[2][4], const u16* Bs, int lane,
                                      f32x4 acc[2][8], int nb) {
#pragma unroll
    for (int n = 0; n < 4; ++n) {
#pragma unroll
        for (int kc = 0; kc < 4; ++kc) {
            f16x8 b = fragS(Bs, n * 16, lane, kc);
            acc[0][nb + n] = __builtin_amdgcn_mfma_f32_16x16x32_f16(a[0][kc], b, acc[0][nb + n], 0, 0, 0);
            acc[1][nb + n] = __builtin_amdgcn_mfma_f32_16x16x32_f16(a[1][kc], b, acc[1][nb + n], 0, 0, 0);
        }
    }
}

// ---- fused SAGE layer (DO=128): OutH = fp16(relu(H@Ws + M@Wn + b))
// As 32KB linear + Bs 16KB (64-row half) = 48KB -> 3 blocks/CU.
// OOB A-rows read garbage inside the workspace (masked at write).
__global__ __launch_bounds__(256) void gemm_sage_f16(
    const u16* H, const u16* M,
    const u16* __restrict__ Ws, const u16* __restrict__ Wn,
    const float* __restrict__ bias, u16* OutH) {
    __shared__ u16 As[128 * 128];
    __shared__ u16 Bs[64 * 128];
    const int tid = threadIdx.x;
    const int lane = tid & 63;
    const int wrow = (tid >> 6) * 32;
    const int row0 = blockIdx.x * 128;

    f32x4 acc[2][8];
#pragma unroll
    for (int rt = 0; rt < 2; ++rt)
#pragma unroll
        for (int n = 0; n < 8; ++n) acc[rt][n] = {0.f, 0.f, 0.f, 0.f};
    f16x8 a[2][4];

    stage128(As, H + (size_t)row0 * 128, tid);
    stage64(Bs, Ws, tid);
    __syncthreads();
    loadA(a, As, wrow, lane);
    mfmaH(a, Bs, lane, acc, 0);
    __syncthreads();
    stage64(Bs, Ws + 64 * 128, tid);
    __syncthreads();
    mfmaH(a, Bs, lane, acc, 4);
    __syncthreads();
    stage128(As, M + (size_t)row0 * 128, tid);
    stage64(Bs, Wn, tid);
    __syncthreads();
    loadA(a, As, wrow, lane);
    mfmaH(a, Bs, lane, acc, 0);
    __syncthreads();
    stage64(Bs, Wn + 64 * 128, tid);
    __syncthreads();
    mfmaH(a, Bs, lane, acc, 4);

    const int cit = lane & 15;
    const int rq = (lane >> 4) * 4;
#pragma unroll
    for (int rt = 0; rt < 2; ++rt)
#pragma unroll
        for (int n = 0; n < 8; ++n) {
            float bv = bias[n * 16 + cit];
            f32x4 v = acc[rt][n];
#pragma unroll
            for (int r = 0; r < 4; ++r) {
                int gr = row0 + wrow + rt * 16 + rq + r;
                if (gr < NN) {
                    float o = fmaxf(v[r] + bv, 0.f);
                    OutH[(size_t)gr * DF + n * 16 + cit] = f2h(o);
                }
            }
        }
}

// ---- layer 2 (128 packed cols): n 0-63 -> selfb = fp16(H@Ws2 + b2);
//      n 64-127 -> g2 = fp16(H@Wn2). W2 rows 0-63 = Ws2^T, 64-127 = Wn2^T.
__global__ __launch_bounds__(256) void gemm_l2_f16(
    const u16* __restrict__ H, const u16* __restrict__ W2,
    const float* __restrict__ b2, u16* __restrict__ selfb, u16* __restrict__ g2) {
    __shared__ u16 As[128 * 128];
    __shared__ u16 Bs[64 * 128];
    const int tid = threadIdx.x;
    const int lane = tid & 63;
    const int wrow = (tid >> 6) * 32;
    const int row0 = blockIdx.x * 128;

    f32x4 acc[2][8];
#pragma unroll
    for (int rt = 0; rt < 2; ++rt)
#pragma unroll
        for (int n = 0; n < 8; ++n) acc[rt][n] = {0.f, 0.f, 0.f, 0.f};
    f16x8 a[2][4];

    stage128(As, H + (size_t)row0 * 128, tid);
    stage64(Bs, W2, tid);
    __syncthreads();
    loadA(a, As, wrow, lane);
    mfmaH(a, Bs, lane, acc, 0);
    __syncthreads();
    stage64(Bs, W2 + 64 * 128, tid);
    __syncthreads();
    mfmaH(a, Bs, lane, acc, 4);

    const int cit = lane & 15;
    const int rq = (lane >> 4) * 4;
#pragma unroll
    for (int rt = 0; rt < 2; ++rt)
#pragma unroll
        for (int n = 0; n < 8; ++n) {
            f32x4 v = acc[rt][n];
            float bv = (n < 4) ? b2[n * 16 + cit] : 0.f;
#pragma unroll
            for (int r = 0; r < 4; ++r) {
                int gr = row0 + wrow + rt * 16 + rq + r;
                if (gr < NN) {
                    if (n < 4) selfb[(size_t)gr * 64 + n * 16 + cit] = f2h(v[r] + bv);
                    else g2[(size_t)gr * 64 + (n - 4) * 16 + cit] = f2h(v[r]);
                }
            }
        }
}

extern "C" void kernel_launch(void* const* d_in, const int* in_sizes, int n_in,
                              void* d_out, int out_size, void* d_ws, size_t ws_size,
                              hipStream_t stream) {
    const float* x   = (const float*)d_in[0];
    const int*   src = (const int*)d_in[1];
    const int*   dst = (const int*)d_in[2];
    const float* Ws0 = (const float*)d_in[3];
    const float* Wn0 = (const float*)d_in[4];
    const float* b0  = (const float*)d_in[5];
    const float* Ws1 = (const float*)d_in[6];
    const float* Wn1 = (const float*)d_in[7];
    const float* b1  = (const float*)d_in[8];
    const float* Ws2 = (const float*)d_in[9];
    const float* Wn2 = (const float*)d_in[10];
    const float* b2  = (const float*)d_in[11];
    float* out = (float*)d_out;

    // workspace (~66 MB):
    int* H       = (int*)d_ws;                 // NH (100096)
    int* O       = H + NH;                     // NH+1 (alloc 100352)
    int* CBT     = O + 100352;                 // NCB (alloc 512)
    int* CBO     = CBT + 512;                  // NCB (alloc 512; unused)
    int* rowptr  = CBO + 512;                  // NN+1 (alloc 100352)
    int* col     = rowptr + 100352;            // NE
    uint32* ebuf = (uint32*)(col + NE);        // NE
    u16* WB      = (u16*)(ebuf + NE);          // 5 * 16384
    u16* W0s = WB, *W0n = WB + 16384, *W1s = WB + 2 * 16384, *W1n = WB + 3 * 16384;
    u16* W2  = WB + 4 * 16384;
    u16* P1 = WB + 5 * 16384;                  // fp16 x -> h1 -> h2 (in-place)
    u16* P3 = P1 + (size_t)NN * DF;            // fp16 mean0/mean1; then g2|self
    u16* G2   = P3;                            // layer-2 neighbor term (NN*64)
    u16* SELF = P3 + (size_t)NN * 64;          // layer-2 self term (NN*64)

    const int gB = (NN + 127) / 128;           // 782

    // ---- front end: CBT zero + (hist | weight-prep | x-cvt) in one dispatch ----
    hipMemsetAsync(CBT, 0, NCB * sizeof(int), stream);
    histA_prep<<<NWA + 320 + NN * DF / 4 / 256, 256, 0, stream>>>(
        dst, H, CBT, Ws0, Wn0, Ws1, Wn1, Ws2, Wn2, WB, x, (uint2*)P1);

    // ---- CSR: scan + two-pass counting sort ----
    scanCBW<<<NCB, 512, 0, stream>>>(CBT, H, O, rowptr);
    passA<<<NWA, 1024, 0, stream>>>(src, dst, O, ebuf);
    passB<<<NCB, 256, 0, stream>>>(ebuf, O, rowptr, col);

    // ---- layer 0 ----
    gather_f16<<<(NN / 32) * 2, 256, 0, stream>>>(P1, rowptr, col, P3);
    gemm_sage_f16<<<gB, 256, 0, stream>>>(P1, P3, W0s, W0n, b0, P1);

    // ---- layer 1 ----
    gather_f16<<<(NN / 32) * 2, 256, 0, stream>>>(P1, rowptr, col, P3);
    gemm_sage_f16<<<gB, 256, 0, stream>>>(P1, P3, W1s, W1n, b1, P1);

    // ---- layer 2 (transform-then-aggregate; self term fp16) ----
    gemm_l2_f16<<<gB, 256, 0, stream>>>(P1, W2, b2, SELF, G2);
    gather_add_f16<<<NN / 32, 256, 0, stream>>>(G2, SELF, rowptr, col, out);
}

// Round 11
// 368.236 us; speedup vs baseline: 1.0438x; 1.0085x over previous
//
#include <hip/hip_runtime.h>

#define NN 100000
#define NE 1600000
#define DF 128
#define NCB 391   // coarse buckets: dst>>8, 256 nodes each
#define NWA 256   // pass-A workgroups (wg-private regions scale with this)
#define SZA 6250  // edges per pass-A stripe (NE/NWA)
#define NH (NCB * NWA)  // 100096
#define CAPB 6144 // pass-B LDS seg capacity (mean 4092 edges/cb, +32 sigma)

typedef unsigned int uint32;
typedef unsigned short u16;
typedef _Float16 f16;
typedef f16 f16x8 __attribute__((ext_vector_type(8)));
typedef f16 f16x2 __attribute__((ext_vector_type(2)));
typedef float f32x4 __attribute__((ext_vector_type(4)));

// ---- fp16 helpers ----
__device__ __forceinline__ uint32 pk2(float a, float b) {
    union { f16x2 h; uint32 u; } v;
    v.h.x = (f16)a; v.h.y = (f16)b;
    return v.u;
}
__device__ __forceinline__ u16 f2h(float a) {
    union { f16 h; u16 u; } v; v.h = (f16)a; return v.u;
}

// ================= CSR build: two-pass counting sort =================
// R5: gathers stay zero-LDS/max-occupancy. R7: launch merging exhausted.
// R8: top-5 visibility dead (harness 256MiB poison fill ~41us in-stream).
// R10: async global_load_lds GEMM staging (neutral -> GEMMs are
// barrier-drain-latency-bound, not staging-bound). R11: prefetch both
// weight halves into double-Bs; gemm_sage 5->3 barriers, gemm_l2 3->1.

// blocks 0..NWA-1:        coarse hist (also atomicAdd -> CBT)
// blocks NWA..NWA+319:    weight prep fp32 [k][n] -> fp16 [n][k]
// blocks NWA+320..:       x fp32 -> fp16
__global__ __launch_bounds__(256) void histA_prep(
    const int* __restrict__ dst, int* __restrict__ H, int* __restrict__ CBT,
    const float* __restrict__ Ws0, const float* __restrict__ Wn0,
    const float* __restrict__ Ws1, const float* __restrict__ Wn1,
    const float* __restrict__ Ws2, const float* __restrict__ Wn2,
    u16* __restrict__ WB,
    const float* __restrict__ x, uint2* __restrict__ xh) {
    __shared__ int lh[NCB];
    int b = blockIdx.x, t = threadIdx.x;
    if (b < NWA) {
        int w = b;
        for (int i = t; i < NCB; i += 256) lh[i] = 0;
        __syncthreads();
        int e0 = w * SZA, e1 = min(e0 + SZA, NE);
        for (int e = e0 + t; e < e1; e += 256) atomicAdd(&lh[dst[e] >> 8], 1);
        __syncthreads();
        for (int i = t; i < NCB; i += 256) {
            int v = lh[i];
            H[i * NWA + w] = v;
            if (v) atomicAdd(&CBT[i], v);  // CBT zeroed by memset node each replay
        }
    } else if (b < NWA + 320) {
        int u = (b - NWA) * 256 + t;  // 0 .. 81919
        if (u < 65536) {
            int m = u >> 14;           // 0..3
            int local = u & 16383;
            int k = local >> 7, n = local & 127;
            const float* W = (m == 0) ? Ws0 : (m == 1) ? Wn0 : (m == 2) ? Ws1 : Wn1;
            WB[m * 16384 + n * 128 + k] = f2h(W[k * 128 + n]);
        } else {
            int local = u - 65536;     // 0 .. 16383
            int half = local >> 13;    // 0 = Ws2, 1 = Wn2
            int idx = local & 8191;
            int k = idx >> 6, n = idx & 63;
            const float* W = half ? Wn2 : Ws2;
            WB[4 * 16384 + (n + half * 64) * 128 + k] = f2h(W[k * 64 + n]);
        }
    } else {
        int u = (b - NWA - 320) * 256 + t;
        if (u < NN * DF / 4) {
            float4 v = ((const float4*)x)[u];
            uint2 o;
            o.x = pk2(v.x, v.y);
            o.y = pk2(v.z, v.w);
            xh[u] = o;
        }
    }
}

// levels 2+3 FUSED: each of 391 wgs redundantly scans the 391
// coarse-bucket totals in LDS, then does its per-cb scan of 256 counts.
__global__ __launch_bounds__(512) void scanCBW(const int* __restrict__ CBT,
                                               const int* __restrict__ H,
                                               int* __restrict__ O,
                                               int* __restrict__ rowptr) {
    __shared__ int sm[512];
    __shared__ int sh[256];
    int cb = blockIdx.x, t = threadIdx.x;
    int v = (t < NCB) ? CBT[t] : 0;
    sm[t] = v;
    __syncthreads();
    for (int off = 1; off < 512; off <<= 1) {
        int x = (t >= off) ? sm[t - off] : 0;
        __syncthreads();
        sm[t] += x;
        __syncthreads();
    }
    if (cb == 0 && t == NCB - 1) {
        O[NH] = sm[t];       // = NE
        rowptr[NN] = sm[t];  // = NE
    }
    int cbo = sm[cb] - CBT[cb];
    int hv = (t < 256) ? H[cb * NWA + t] : 0;
    if (t < 256) sh[t] = hv;
    __syncthreads();
    for (int off = 1; off < 256; off <<= 1) {
        int x = (t >= off && t < 256) ? sh[t - off] : 0;
        __syncthreads();
        if (t < 256) sh[t] += x;
        __syncthreads();
    }
    if (t < 256) O[cb * NWA + t] = cbo + sh[t] - hv;
}

__global__ __launch_bounds__(1024) void passA(const int* __restrict__ src,
                                              const int* __restrict__ dst,
                                              const int* __restrict__ O,
                                              uint32* __restrict__ ebuf) {
    __shared__ int cur[NCB];
    int w = blockIdx.x, t = threadIdx.x;
    for (int i = t; i < NCB; i += 1024) cur[i] = O[i * NWA + w];
    __syncthreads();
    int e0 = w * SZA, e1 = min(e0 + SZA, NE);
    for (int e = e0 + t; e < e1; e += 1024) {
        int d = dst[e];
        int cb = d >> 8;
        int p = atomicAdd(&cur[cb], 1);  // LDS atomic; region private to this wg
        ebuf[p] = ((uint32)src[e] << 8) | (uint32)(d & 255);
    }
}

__global__ __launch_bounds__(256) void passB(const uint32* __restrict__ ebuf,
                                             const int* __restrict__ O,
                                             int* __restrict__ rowptr,
                                             int* __restrict__ col) {
    __shared__ int hist[256], start[256], cur[256];
    __shared__ int seg[CAPB];
    int cb = blockIdx.x, t = threadIdx.x;
    int base = O[cb * NWA], end = O[(cb + 1) * NWA];
    int m = end - base;
    hist[t] = 0;
    __syncthreads();
    for (int i = t; i < m; i += 256) atomicAdd(&hist[ebuf[base + i] & 255], 1);
    __syncthreads();
    int v = hist[t];
    cur[t] = v;
    __syncthreads();
    for (int off = 1; off < 256; off <<= 1) {
        int x = (t >= off) ? cur[t - off] : 0;
        __syncthreads();
        cur[t] += x;
        __syncthreads();
    }
    start[t] = cur[t] - v;
    __syncthreads();
    int node = cb * 256 + t;
    if (node < NN) rowptr[node] = base + start[t];
    cur[t] = start[t];
    __syncthreads();
    if (m <= CAPB) {  // fast path: sort into LDS, stream out coalesced
        for (int i = t; i < m; i += 256) {
            uint32 u = ebuf[base + i];
            int p = atomicAdd(&cur[u & 255], 1);
            seg[p] = (int)(u >> 8);
        }
        __syncthreads();
        for (int i = t; i < m; i += 256) col[base + i] = seg[i];
    } else {  // correctness fallback
        for (int i = t; i < m; i += 256) {
            uint32 u = ebuf[base + i];
            int p = atomicAdd(&cur[u & 255], 1);
            col[base + p] = (int)(u >> 8);
        }
    }
}

// ================= gather mean, fp16 in/out, width 128 ==================
// Single launch, panel = bid&1. 8 lanes/node, dwordx4/lane/neighbor,
// unroll 8, zero LDS. At the ~3 TB/s random-line fill-port ceiling.
__global__ __launch_bounds__(256) void gather_f16(const u16* __restrict__ hb,
                                                  const int* __restrict__ rowptr,
                                                  const int* __restrict__ col,
                                                  u16* __restrict__ mean) {
    int bid = blockIdx.x;
    int panel = bid & 1;                       // 0: cols 0-63, 1: cols 64-127
    int node = (bid >> 1) * 32 + (threadIdx.x >> 3);
    int g = threadIdx.x & 7;                   // 16B chunk within 128B panel
    const u16* hp = hb + panel * 64 + g * 8;
    int s = rowptr[node], e = rowptr[node + 1];
    float acc[8];
#pragma unroll
    for (int i = 0; i < 8; ++i) acc[i] = 0.f;
    int j = s;
    for (; j + 7 < e; j += 8) {
        int n0 = col[j],     n1 = col[j + 1], n2 = col[j + 2], n3 = col[j + 3];
        int n4 = col[j + 4], n5 = col[j + 5], n6 = col[j + 6], n7 = col[j + 7];
        f16x8 v0 = *(const f16x8*)(hp + (size_t)n0 * DF);
        f16x8 v1 = *(const f16x8*)(hp + (size_t)n1 * DF);
        f16x8 v2 = *(const f16x8*)(hp + (size_t)n2 * DF);
        f16x8 v3 = *(const f16x8*)(hp + (size_t)n3 * DF);
        f16x8 v4 = *(const f16x8*)(hp + (size_t)n4 * DF);
        f16x8 v5 = *(const f16x8*)(hp + (size_t)n5 * DF);
        f16x8 v6 = *(const f16x8*)(hp + (size_t)n6 * DF);
        f16x8 v7 = *(const f16x8*)(hp + (size_t)n7 * DF);
        f16x8 sA = (v0 + v1) + (v2 + v3);
        f16x8 sB = (v4 + v5) + (v6 + v7);
#pragma unroll
        for (int i = 0; i < 8; ++i) acc[i] += (float)sA[i] + (float)sB[i];
    }
    for (; j + 3 < e; j += 4) {
        int n0 = col[j], n1 = col[j + 1], n2 = col[j + 2], n3 = col[j + 3];
        f16x8 v0 = *(const f16x8*)(hp + (size_t)n0 * DF);
        f16x8 v1 = *(const f16x8*)(hp + (size_t)n1 * DF);
        f16x8 v2 = *(const f16x8*)(hp + (size_t)n2 * DF);
        f16x8 v3 = *(const f16x8*)(hp + (size_t)n3 * DF);
        f16x8 sv = (v0 + v1) + (v2 + v3);
#pragma unroll
        for (int i = 0; i < 8; ++i) acc[i] += (float)sv[i];
    }
    for (; j < e; ++j) {
        f16x8 v = *(const f16x8*)(hp + (size_t)col[j] * DF);
#pragma unroll
        for (int i = 0; i < 8; ++i) acc[i] += (float)v[i];
    }
    float invd = 1.f / fmaxf((float)(e - s), 1.f);
    union { f16x8 h; uint4 u; } o;
#pragma unroll
    for (int i = 0; i < 8; ++i) o.h[i] = (f16)(acc[i] * invd);
    *(uint4*)(mean + (size_t)node * DF + panel * 64 + g * 8) = o.u;
}

// ========== gather mean-add, fp16 in, width 64: out = self + mean(g2) =====
__global__ __launch_bounds__(256) void gather_add_f16(const u16* __restrict__ gb,
                                                      const u16* __restrict__ selfb,
                                                      const int* __restrict__ rowptr,
                                                      const int* __restrict__ col,
                                                      float* __restrict__ out) {
    int node = blockIdx.x * 32 + (threadIdx.x >> 3);
    int g = threadIdx.x & 7;  // 16B chunk within the 128B row
    int s = rowptr[node], e = rowptr[node + 1];
    float acc[8];
#pragma unroll
    for (int i = 0; i < 8; ++i) acc[i] = 0.f;
    int j = s;
    for (; j + 7 < e; j += 8) {
        int n0 = col[j],     n1 = col[j + 1], n2 = col[j + 2], n3 = col[j + 3];
        int n4 = col[j + 4], n5 = col[j + 5], n6 = col[j + 6], n7 = col[j + 7];
        f16x8 v0 = *(const f16x8*)(gb + (size_t)n0 * 64 + g * 8);
        f16x8 v1 = *(const f16x8*)(gb + (size_t)n1 * 64 + g * 8);
        f16x8 v2 = *(const f16x8*)(gb + (size_t)n2 * 64 + g * 8);
        f16x8 v3 = *(const f16x8*)(gb + (size_t)n3 * 64 + g * 8);
        f16x8 v4 = *(const f16x8*)(gb + (size_t)n4 * 64 + g * 8);
        f16x8 v5 = *(const f16x8*)(gb + (size_t)n5 * 64 + g * 8);
        f16x8 v6 = *(const f16x8*)(gb + (size_t)n6 * 64 + g * 8);
        f16x8 v7 = *(const f16x8*)(gb + (size_t)n7 * 64 + g * 8);
        f16x8 sA = (v0 + v1) + (v2 + v3);
        f16x8 sB = (v4 + v5) + (v6 + v7);
#pragma unroll
        for (int i = 0; i < 8; ++i) acc[i] += (float)sA[i] + (float)sB[i];
    }
    for (; j + 3 < e; j += 4) {
        int n0 = col[j], n1 = col[j + 1], n2 = col[j + 2], n3 = col[j + 3];
        f16x8 v0 = *(const f16x8*)(gb + (size_t)n0 * 64 + g * 8);
        f16x8 v1 = *(const f16x8*)(gb + (size_t)n1 * 64 + g * 8);
        f16x8 v2 = *(const f16x8*)(gb + (size_t)n2 * 64 + g * 8);
        f16x8 v3 = *(const f16x8*)(gb + (size_t)n3 * 64 + g * 8);
        f16x8 sv = (v0 + v1) + (v2 + v3);
#pragma unroll
        for (int i = 0; i < 8; ++i) acc[i] += (float)sv[i];
    }
    for (; j < e; ++j) {
        f16x8 v = *(const f16x8*)(gb + (size_t)col[j] * 64 + g * 8);
#pragma unroll
        for (int i = 0; i < 8; ++i) acc[i] += (float)v[i];
    }
    float invd = 1.f / fmaxf((float)(e - s), 1.f);
    f16x8 sv = *(const f16x8*)(selfb + (size_t)node * 64 + g * 8);
    float4 a, b;
    a.x = (float)sv[0] + acc[0] * invd; a.y = (float)sv[1] + acc[1] * invd;
    a.z = (float)sv[2] + acc[2] * invd; a.w = (float)sv[3] + acc[3] * invd;
    b.x = (float)sv[4] + acc[4] * invd; b.y = (float)sv[5] + acc[5] * invd;
    b.z = (float)sv[6] + acc[6] * invd; b.w = (float)sv[7] + acc[7] * invd;
    float4* op = (float4*)(out + (size_t)node * 64 + g * 8);
    op[0] = a; op[1] = b;
}

// ================= MFMA GEMM (fp16), async-staged, double-Bs =============
// Staging: global_load_lds width=16 into LINEAR LDS, chunk-XOR swizzle on
// BOTH global source and ds_read (rule #21). R11: both 64-row weight
// halves prefetched into Bs0|Bs1 before the barrier -> mfma halves run
// back-to-back; gemm_sage 3 barriers, gemm_l2 1. LDS 64KB -> 2 blocks/CU.
__device__ __forceinline__ void gl_lds16(const u16* g, u16* l) {
    __builtin_amdgcn_global_load_lds(
        (const __attribute__((address_space(1))) void*)g,
        (__attribute__((address_space(3))) void*)l, 16, 0, 0);
}

// stage 128 rows of 256B from g into lds (linear, swizzled). 8 calls/wave.
__device__ __forceinline__ void stage128(u16* lds, const u16* g, int tid) {
    int lane = tid & 63, wid = tid >> 6;
#pragma unroll
    for (int i = 0; i < 8; ++i) {
        int r4 = (wid + i * 4) * 4;        // 4 rows per call, waves interleaved
        int row = r4 + (lane >> 4);
        int c = lane & 15;
        gl_lds16(g + (size_t)row * 128 + ((c ^ (row & 7)) * 8), lds + r4 * 128);
    }
}

// stage 64 rows (weight half). 4 calls/wave.
__device__ __forceinline__ void stage64(u16* lds, const u16* g, int tid) {
    int lane = tid & 63, wid = tid >> 6;
#pragma unroll
    for (int i = 0; i < 4; ++i) {
        int r4 = (wid + i * 4) * 4;
        int row = r4 + (lane >> 4);
        int c = lane & 15;
        gl_lds16(g + (size_t)row * 128 + ((c ^ (row & 7)) * 8), lds + r4 * 128);
    }
}

__device__ __forceinline__ f16x8 fragS(const u16* sm, int row, int lane, int kc) {
    int r = row + (lane & 15);
    int c = (kc * 4 + (lane >> 4)) ^ (r & 7);
    return *(const f16x8*)(sm + r * 128 + c * 8);
}

__device__ __forceinline__ void loadA(f16x8 a[2][4], const u16* As, int wrow, int lane) {
#pragma unroll
    for (int rt = 0; rt < 2; ++rt)
#pragma unroll
        for (int kc = 0; kc < 4; ++kc) a[rt][kc] = fragS(As, wrow + rt * 16, lane, kc);
}

// one 64-col weight half: n-tiles nb..nb+3
__device__ __forceinline__ void mfmaH(const f16x8 a[2][4], const u16* Bs, int lane,
                                      f32x4 acc[2][8], int nb) {
#pragma unroll
    for (int n = 0; n < 4; ++n) {
#pragma unroll
        for (int kc = 0; kc < 4; ++kc) {
            f16x8 b = fragS(Bs, n * 16, lane, kc);
            acc[0][nb + n] = __builtin_amdgcn_mfma_f32_16x16x32_f16(a[0][kc], b, acc[0][nb + n], 0, 0, 0);
            acc[1][nb + n] = __builtin_amdgcn_mfma_f32_16x16x32_f16(a[1][kc], b, acc[1][nb + n], 0, 0, 0);
        }
    }
}

// ---- fused SAGE layer (DO=128): OutH = fp16(relu(H@Ws + M@Wn + b))
// As 32KB + Bs0/Bs1 16KB each = 64KB -> 2 blocks/CU. 3 barriers.
// OOB A-rows read garbage inside the workspace (masked at write).
__global__ __launch_bounds__(256) void gemm_sage_f16(
    const u16* H, const u16* M,
    const u16* __restrict__ Ws, const u16* __restrict__ Wn,
    const float* __restrict__ bias, u16* OutH) {
    __shared__ u16 As[128 * 128];
    __shared__ u16 Bs0[64 * 128];
    __shared__ u16 Bs1[64 * 128];
    const int tid = threadIdx.x;
    const int lane = tid & 63;
    const int wrow = (tid >> 6) * 32;
    const int row0 = blockIdx.x * 128;

    f32x4 acc[2][8];
#pragma unroll
    for (int rt = 0; rt < 2; ++rt)
#pragma unroll
        for (int n = 0; n < 8; ++n) acc[rt][n] = {0.f, 0.f, 0.f, 0.f};
    f16x8 a[2][4];

    stage128(As, H + (size_t)row0 * 128, tid);
    stage64(Bs0, Ws, tid);
    stage64(Bs1, Ws + 64 * 128, tid);
    __syncthreads();
    loadA(a, As, wrow, lane);
    mfmaH(a, Bs0, lane, acc, 0);
    mfmaH(a, Bs1, lane, acc, 4);
    __syncthreads();
    stage128(As, M + (size_t)row0 * 128, tid);
    stage64(Bs0, Wn, tid);
    stage64(Bs1, Wn + 64 * 128, tid);
    __syncthreads();
    loadA(a, As, wrow, lane);
    mfmaH(a, Bs0, lane, acc, 0);
    mfmaH(a, Bs1, lane, acc, 4);

    const int cit = lane & 15;
    const int rq = (lane >> 4) * 4;
#pragma unroll
    for (int rt = 0; rt < 2; ++rt)
#pragma unroll
        for (int n = 0; n < 8; ++n) {
            float bv = bias[n * 16 + cit];
            f32x4 v = acc[rt][n];
#pragma unroll
            for (int r = 0; r < 4; ++r) {
                int gr = row0 + wrow + rt * 16 + rq + r;
                if (gr < NN) {
                    float o = fmaxf(v[r] + bv, 0.f);
                    OutH[(size_t)gr * DF + n * 16 + cit] = f2h(o);
                }
            }
        }
}

// ---- layer 2 (128 packed cols): n 0-63 -> selfb = fp16(H@Ws2 + b2);
//      n 64-127 -> g2 = fp16(H@Wn2). W2 rows 0-63 = Ws2^T, 64-127 = Wn2^T.
//      Single barrier (full W2 prefetched into Bs0|Bs1).
__global__ __launch_bounds__(256) void gemm_l2_f16(
    const u16* __restrict__ H, const u16* __restrict__ W2,
    const float* __restrict__ b2, u16* __restrict__ selfb, u16* __restrict__ g2) {
    __shared__ u16 As[128 * 128];
    __shared__ u16 Bs0[64 * 128];
    __shared__ u16 Bs1[64 * 128];
    const int tid = threadIdx.x;
    const int lane = tid & 63;
    const int wrow = (tid >> 6) * 32;
    const int row0 = blockIdx.x * 128;

    f32x4 acc[2][8];
#pragma unroll
    for (int rt = 0; rt < 2; ++rt)
#pragma unroll
        for (int n = 0; n < 8; ++n) acc[rt][n] = {0.f, 0.f, 0.f, 0.f};
    f16x8 a[2][4];

    stage128(As, H + (size_t)row0 * 128, tid);
    stage64(Bs0, W2, tid);
    stage64(Bs1, W2 + 64 * 128, tid);
    __syncthreads();
    loadA(a, As, wrow, lane);
    mfmaH(a, Bs0, lane, acc, 0);
    mfmaH(a, Bs1, lane, acc, 4);

    const int cit = lane & 15;
    const int rq = (lane >> 4) * 4;
#pragma unroll
    for (int rt = 0; rt < 2; ++rt)
#pragma unroll
        for (int n = 0; n < 8; ++n) {
            f32x4 v = acc[rt][n];
            float bv = (n < 4) ? b2[n * 16 + cit] : 0.f;
#pragma unroll
            for (int r = 0; r < 4; ++r) {
                int gr = row0 + wrow + rt * 16 + rq + r;
                if (gr < NN) {
                    if (n < 4) selfb[(size_t)gr * 64 + n * 16 + cit] = f2h(v[r] + bv);
                    else g2[(size_t)gr * 64 + (n - 4) * 16 + cit] = f2h(v[r]);
                }
            }
        }
}

extern "C" void kernel_launch(void* const* d_in, const int* in_sizes, int n_in,
                              void* d_out, int out_size, void* d_ws, size_t ws_size,
                              hipStream_t stream) {
    const float* x   = (const float*)d_in[0];
    const int*   src = (const int*)d_in[1];
    const int*   dst = (const int*)d_in[2];
    const float* Ws0 = (const float*)d_in[3];
    const float* Wn0 = (const float*)d_in[4];
    const float* b0  = (const float*)d_in[5];
    const float* Ws1 = (const float*)d_in[6];
    const float* Wn1 = (const float*)d_in[7];
    const float* b1  = (const float*)d_in[8];
    const float* Ws2 = (const float*)d_in[9];
    const float* Wn2 = (const float*)d_in[10];
    const float* b2  = (const float*)d_in[11];
    float* out = (float*)d_out;

    // workspace (~66 MB):
    int* H       = (int*)d_ws;                 // NH (100096)
    int* O       = H + NH;                     // NH+1 (alloc 100352)
    int* CBT     = O + 100352;                 // NCB (alloc 512)
    int* CBO     = CBT + 512;                  // NCB (alloc 512; unused)
    int* rowptr  = CBO + 512;                  // NN+1 (alloc 100352)
    int* col     = rowptr + 100352;            // NE
    uint32* ebuf = (uint32*)(col + NE);        // NE
    u16* WB      = (u16*)(ebuf + NE);          // 5 * 16384
    u16* W0s = WB, *W0n = WB + 16384, *W1s = WB + 2 * 16384, *W1n = WB + 3 * 16384;
    u16* W2  = WB + 4 * 16384;
    u16* P1 = WB + 5 * 16384;                  // fp16 x -> h1 -> h2 (in-place)
    u16* P3 = P1 + (size_t)NN * DF;            // fp16 mean0/mean1; then g2|self
    u16* G2   = P3;                            // layer-2 neighbor term (NN*64)
    u16* SELF = P3 + (size_t)NN * 64;          // layer-2 self term (NN*64)

    const int gB = (NN + 127) / 128;           // 782

    // ---- front end: CBT zero + (hist | weight-prep | x-cvt) in one dispatch ----
    hipMemsetAsync(CBT, 0, NCB * sizeof(int), stream);
    histA_prep<<<NWA + 320 + NN * DF / 4 / 256, 256, 0, stream>>>(
        dst, H, CBT, Ws0, Wn0, Ws1, Wn1, Ws2, Wn2, WB, x, (uint2*)P1);

    // ---- CSR: scan + two-pass counting sort ----
    scanCBW<<<NCB, 512, 0, stream>>>(CBT, H, O, rowptr);
    passA<<<NWA, 1024, 0, stream>>>(src, dst, O, ebuf);
    passB<<<NCB, 256, 0, stream>>>(ebuf, O, rowptr, col);

    // ---- layer 0 ----
    gather_f16<<<(NN / 32) * 2, 256, 0, stream>>>(P1, rowptr, col, P3);
    gemm_sage_f16<<<gB, 256, 0, stream>>>(P1, P3, W0s, W0n, b0, P1);

    // ---- layer 1 ----
    gather_f16<<<(NN / 32) * 2, 256, 0, stream>>>(P1, rowptr, col, P3);
    gemm_sage_f16<<<gB, 256, 0, stream>>>(P1, P3, W1s, W1n, b1, P1);

    // ---- layer 2 (transform-then-aggregate; self term fp16) ----
    gemm_l2_f16<<<gB, 256, 0, stream>>>(P1, W2, b2, SELF, G2);
    gather_add_f16<<<NN / 32, 256, 0, stream>>>(G2, SELF, rowptr, col, out);
}